// Round 1
// baseline (537.943 us; speedup 1.0000x reference)
//
#include <hip/hip_runtime.h>

// Problem constants (fixed by the reference): B=16, C=384, H=W=64 -> N=4096, HEADS=8, CH=48.
#define CB 384
#define NB 4096

typedef float f32x4 __attribute__((ext_vector_type(4)));
typedef __bf16 bf16x8 __attribute__((ext_vector_type(8)));

// ---------- helpers ----------
__device__ __forceinline__ void cvt8(const float* __restrict__ src, __bf16* dst) {
  float4 f0 = *(const float4*)src;
  float4 f1 = *(const float4*)(src + 4);
  bf16x8 v = { (__bf16)f0.x, (__bf16)f0.y, (__bf16)f0.z, (__bf16)f0.w,
               (__bf16)f1.x, (__bf16)f1.y, (__bf16)f1.z, (__bf16)f1.w };
  *(bf16x8*)dst = v;
}

// ---------- K0: xsum[b][c] = sum_n x[b][c][n] ----------
__global__ __launch_bounds__(256) void k_xsum(const float* __restrict__ x, float* __restrict__ xsum) {
  const float4* r4 = (const float4*)(x + (size_t)blockIdx.x * NB);
  float s = 0.f;
  for (int j = threadIdx.x; j < NB / 4; j += 256) { float4 f = r4[j]; s += (f.x + f.y) + (f.z + f.w); }
  #pragma unroll
  for (int off = 32; off > 0; off >>= 1) s += __shfl_down(s, off);
  __shared__ float wsum[4];
  if ((threadIdx.x & 63) == 0) wsum[threadIdx.x >> 6] = s;
  __syncthreads();
  if (threadIdx.x == 0) xsum[blockIdx.x] = (wsum[0] + wsum[1]) + (wsum[2] + wsum[3]);
}

// ---------- K0b: Wcat(bf16) = [w1; w2]  (768 x 384) ----------
__global__ __launch_bounds__(256) void k_wcat(const float* __restrict__ w1, const float* __restrict__ w2,
                                              __bf16* __restrict__ Wc) {
  int i = blockIdx.x * 256 + threadIdx.x;  // float4 index; total 2*147456/4 = 73728
  float4 f = (i < 36864) ? ((const float4*)w1)[i] : ((const float4*)w2)[i - 36864];
  __bf16* d = Wc + (size_t)i * 4;
  d[0] = (__bf16)f.x; d[1] = (__bf16)f.y; d[2] = (__bf16)f.z; d[3] = (__bf16)f.w;
}

// ---------- K1: G_b = x_b x_b^T  (bf16 out, MFMA) ----------
// grid (9, 16): blockIdx.x = 3*tr + tc (128x128 tile), blockIdx.y = b
__global__ __launch_bounds__(256) void k_gram(const float* __restrict__ x, __bf16* __restrict__ Gb) {
  int b = blockIdx.y;
  int tr = blockIdx.x / 3, tc = blockIdx.x % 3;
  const float* xb = x + (size_t)b * CB * NB;
  __shared__ __align__(16) __bf16 As[128][72];
  __shared__ __align__(16) __bf16 Bs[128][72];
  int tid = threadIdx.x, lane = tid & 63;
  int wr = (tid >> 6) >> 1, wc = (tid >> 6) & 1;
  int rrow = lane & 15, kgrp = lane >> 4;
  f32x4 zero = {0.f, 0.f, 0.f, 0.f};
  f32x4 acc[4][4];
  #pragma unroll
  for (int i = 0; i < 4; ++i)
    #pragma unroll
    for (int j = 0; j < 4; ++j) acc[i][j] = zero;
  int sr = tid >> 1, sh = (tid & 1) * 32;
  const float* pa = xb + (size_t)(tr * 128 + sr) * NB + sh;
  const float* pb = xb + (size_t)(tc * 128 + sr) * NB + sh;
  for (int k0 = 0; k0 < NB; k0 += 64) {
    #pragma unroll
    for (int j = 0; j < 4; ++j) cvt8(pa + k0 + j * 8, &As[sr][sh + j * 8]);
    #pragma unroll
    for (int j = 0; j < 4; ++j) cvt8(pb + k0 + j * 8, &Bs[sr][sh + j * 8]);
    __syncthreads();
    #pragma unroll
    for (int kk = 0; kk < 2; ++kk) {
      int ko = kk * 32 + kgrp * 8;
      bf16x8 af[4], bg[4];
      #pragma unroll
      for (int i = 0; i < 4; ++i) af[i] = *(const bf16x8*)&As[wr * 64 + i * 16 + rrow][ko];
      #pragma unroll
      for (int j = 0; j < 4; ++j) bg[j] = *(const bf16x8*)&Bs[wc * 64 + j * 16 + rrow][ko];
      #pragma unroll
      for (int i = 0; i < 4; ++i)
        #pragma unroll
        for (int j = 0; j < 4; ++j)
          acc[i][j] = __builtin_amdgcn_mfma_f32_16x16x32_bf16(af[i], bg[j], acc[i][j], 0, 0, 0);
    }
    __syncthreads();
  }
  __bf16* gb = Gb + (size_t)b * CB * CB;
  #pragma unroll
  for (int i = 0; i < 4; ++i)
    #pragma unroll
    for (int rr = 0; rr < 4; ++rr) {
      int row = tr * 128 + wr * 64 + i * 16 + kgrp * 4 + rr;
      #pragma unroll
      for (int j = 0; j < 4; ++j) {
        int col = tc * 128 + wc * 64 + j * 16 + rrow;
        gb[(size_t)row * CB + col] = (__bf16)acc[i][j][rr];
      }
    }
}

// ---------- K2: T_b = Wcat(bf16) @ G_b(bf16)  -> fp32 [768][384] ----------
// grid (18, 16): blockIdx.x = 3*tr + tc  (tr 0..5, tc 0..2)
__global__ __launch_bounds__(256) void k_wg(const __bf16* __restrict__ Wc, const __bf16* __restrict__ Gb,
                                            float* __restrict__ T) {
  int b = blockIdx.y;
  int tr = blockIdx.x / 3, tc = blockIdx.x % 3;
  __shared__ __align__(16) __bf16 As[128][72];
  __shared__ __align__(16) __bf16 Bs[128][72];
  int tid = threadIdx.x, lane = tid & 63;
  int wr = (tid >> 6) >> 1, wc = (tid >> 6) & 1;
  int rrow = lane & 15, kgrp = lane >> 4;
  f32x4 zero = {0.f, 0.f, 0.f, 0.f};
  f32x4 acc[4][4];
  #pragma unroll
  for (int i = 0; i < 4; ++i)
    #pragma unroll
    for (int j = 0; j < 4; ++j) acc[i][j] = zero;
  int sr = tid >> 1, sh = (tid & 1) * 32;
  const __bf16* pa = Wc + (size_t)(tr * 128 + sr) * CB + sh;
  // B-frag needs G[k][col]; G is symmetric so stage rows (colbase+sr) directly.
  const __bf16* pb = Gb + (size_t)b * CB * CB + (size_t)(tc * 128 + sr) * CB + sh;
  for (int k0 = 0; k0 < CB; k0 += 64) {
    #pragma unroll
    for (int j = 0; j < 4; ++j) {
      *(bf16x8*)&As[sr][sh + j * 8] = *(const bf16x8*)(pa + k0 + j * 8);
      *(bf16x8*)&Bs[sr][sh + j * 8] = *(const bf16x8*)(pb + k0 + j * 8);
    }
    __syncthreads();
    #pragma unroll
    for (int kk = 0; kk < 2; ++kk) {
      int ko = kk * 32 + kgrp * 8;
      bf16x8 af[4], bg[4];
      #pragma unroll
      for (int i = 0; i < 4; ++i) af[i] = *(const bf16x8*)&As[wr * 64 + i * 16 + rrow][ko];
      #pragma unroll
      for (int j = 0; j < 4; ++j) bg[j] = *(const bf16x8*)&Bs[wc * 64 + j * 16 + rrow][ko];
      #pragma unroll
      for (int i = 0; i < 4; ++i)
        #pragma unroll
        for (int j = 0; j < 4; ++j)
          acc[i][j] = __builtin_amdgcn_mfma_f32_16x16x32_bf16(af[i], bg[j], acc[i][j], 0, 0, 0);
    }
    __syncthreads();
  }
  float* tb = T + (size_t)b * 768 * CB;
  #pragma unroll
  for (int i = 0; i < 4; ++i)
    #pragma unroll
    for (int rr = 0; rr < 4; ++rr) {
      int row = tr * 128 + wr * 64 + i * 16 + kgrp * 4 + rr;
      #pragma unroll
      for (int j = 0; j < 4; ++j) {
        int col = tc * 128 + wc * 64 + j * 16 + rrow;
        tb[(size_t)row * CB + col] = acc[i][j][rr];
      }
    }
}

// ---------- K3: per (b,h) attention algebra -> F(bf16), evec ----------
// grid (8, 16)
__global__ __launch_bounds__(256) void k_attn(
    const float* __restrict__ w1, const float* __restrict__ b1,
    const float* __restrict__ w2, const float* __restrict__ b2,
    const float* __restrict__ w3, const float* __restrict__ b3,
    const float* __restrict__ temp, const float* __restrict__ xsum,
    const float* __restrict__ T, __bf16* __restrict__ Fb, float* __restrict__ evec) {
  int b = blockIdx.y, h = blockIdx.x, tid = threadIdx.x;
  int c0 = h * 48;
  __shared__ float xsuml[384];
  __shared__ float cA[48][133];
  __shared__ float cB[48][133];
  __shared__ float Sl[48][49];
  __shared__ float nq[48], nk[48], wx1[48], wx2[48];

  for (int i = tid; i < 384; i += 256) xsuml[i] = xsum[b * CB + i];
  __syncthreads();

  // phase 1: per-row  wxs = W.row . xsum   and  rowdot = T.row . W.row  -> norms
  if (tid < 96) {
    int r = tid % 48;
    bool isq = tid < 48;
    const float* wrow = (isq ? w1 : w2) + (size_t)(c0 + r) * CB;
    const float* trow = T + ((size_t)b * 768 + (isq ? 0 : 384) + c0 + r) * CB;
    float s1 = 0.f, s2 = 0.f;
    #pragma unroll 4
    for (int e = 0; e < CB; ++e) { float w = wrow[e]; s1 += w * xsuml[e]; s2 += w * trow[e]; }
    float bb = (isq ? b1 : b2)[c0 + r];
    float n2 = s2 + 2.f * bb * s1 + 4096.f * bb * bb;
    float nv = fmaxf(sqrtf(fmaxf(n2, 0.f)), 1e-12f);
    if (isq) { wx1[r] = s1; nq[r] = nv; } else { wx2[r] = s1; nk[r] = nv; }
  }
  __syncthreads();

  // phase 2: S = T1 @ W2_h^T, chunked over e
  float sacc[12];
  #pragma unroll
  for (int i = 0; i < 12; ++i) sacc[i] = 0.f;
  int cc = tid % 48, dq = tid / 48;
  for (int ch = 0; ch < 3; ++ch) {
    for (int idx = tid; idx < 1536; idx += 256) {
      int row = idx >> 5, q4 = (idx & 31) * 4;
      float4 fa = *(const float4*)(T + ((size_t)b * 768 + c0 + row) * CB + ch * 128 + q4);
      float4 fw = *(const float4*)(w2 + (size_t)(c0 + row) * CB + ch * 128 + q4);
      cA[row][q4 + 0] = fa.x; cA[row][q4 + 1] = fa.y; cA[row][q4 + 2] = fa.z; cA[row][q4 + 3] = fa.w;
      cB[row][q4 + 0] = fw.x; cB[row][q4 + 1] = fw.y; cB[row][q4 + 2] = fw.z; cB[row][q4 + 3] = fw.w;
    }
    __syncthreads();
    if (tid < 192) {
      for (int e = 0; e < 128; ++e) {
        float av = cA[cc][e];
        #pragma unroll
        for (int i = 0; i < 12; ++i) sacc[i] += av * cB[dq * 12 + i][e];
      }
    }
    __syncthreads();
  }
  if (tid < 192) {
    float b1c = b1[c0 + cc];
    float th = temp[h];
    #pragma unroll
    for (int i = 0; i < 12; ++i) {
      int d = dq * 12 + i;
      float b2d = b2[c0 + d];
      float sraw = sacc[i] + b1c * wx2[d] + b2d * wx1[cc] + 4096.f * b1c * b2d;
      Sl[cc][d] = th * sraw / (nq[cc] * nk[d]);
    }
  }
  __syncthreads();

  // phase 3: softmax rows + evec
  if (tid < 48) {
    float m = -1e30f;
    #pragma unroll 4
    for (int d = 0; d < 48; ++d) m = fmaxf(m, Sl[tid][d]);
    float ssum = 0.f;
    #pragma unroll 4
    for (int d = 0; d < 48; ++d) { float p = __expf(Sl[tid][d] - m); Sl[tid][d] = p; ssum += p; }
    float inv = 1.f / ssum;
    float ev = 0.f;
    #pragma unroll 4
    for (int d = 0; d < 48; ++d) { float a_ = Sl[tid][d] * inv; Sl[tid][d] = a_; ev += a_ * b3[c0 + d]; }
    evec[b * CB + c0 + tid] = b3[c0 + tid] + ev;
  }
  __syncthreads();

  // phase 4: F rows of this head: F[c'] = W3[c'] + attn[c] @ W3_head + I
  for (int ch = 0; ch < 3; ++ch) {
    for (int idx = tid; idx < 1536; idx += 256) {
      int row = idx >> 5, q4 = (idx & 31) * 4;
      float4 fw = *(const float4*)(w3 + (size_t)(c0 + row) * CB + ch * 128 + q4);
      cB[row][q4 + 0] = fw.x; cB[row][q4 + 1] = fw.y; cB[row][q4 + 2] = fw.z; cB[row][q4 + 3] = fw.w;
    }
    __syncthreads();
    for (int idx = tid; idx < 6144; idx += 256) {
      int c = idx >> 7, a = idx & 127;
      float acc = cB[c][a];
      #pragma unroll 8
      for (int d = 0; d < 48; ++d) acc += Sl[c][d] * cB[d][a];
      int ga = ch * 128 + a;
      float val = acc + ((ga == c0 + c) ? 1.f : 0.f);
      Fb[((size_t)b * CB + c0 + c) * CB + ga] = (__bf16)val;
    }
    __syncthreads();
  }
}

// ---------- K4: out_b = F_b @ x_b + e_b ----------
// grid (96, 16): blockIdx.x = tn*3 + tr
__global__ __launch_bounds__(256) void k_out(const __bf16* __restrict__ Fb, const float* __restrict__ x,
                                             const float* __restrict__ evec, float* __restrict__ out) {
  int b = blockIdx.y;
  int tr = blockIdx.x % 3, tn = blockIdx.x / 3;
  __shared__ __align__(16) __bf16 As[128][72];
  __shared__ __align__(16) __bf16 Bs[128][72];  // [n_local][k]
  int tid = threadIdx.x, lane = tid & 63;
  int wr = (tid >> 6) >> 1, wc = (tid >> 6) & 1;
  int rrow = lane & 15, kgrp = lane >> 4;
  f32x4 zero = {0.f, 0.f, 0.f, 0.f};
  f32x4 acc[4][4];
  #pragma unroll
  for (int i = 0; i < 4; ++i)
    #pragma unroll
    for (int j = 0; j < 4; ++j) acc[i][j] = zero;
  int sr = tid >> 1, sh = (tid & 1) * 32;
  const __bf16* pa = Fb + ((size_t)b * CB + tr * 128 + sr) * CB + sh;
  int ba = tid >> 2, bq = tid & 3;
  const float* pxbase = x + ((size_t)b * CB + ba) * NB + tn * 128 + bq * 32;
  for (int k0 = 0; k0 < CB; k0 += 64) {
    #pragma unroll
    for (int j = 0; j < 4; ++j)
      *(bf16x8*)&As[sr][sh + j * 8] = *(const bf16x8*)(pa + k0 + j * 8);
    const float* px = pxbase + (size_t)k0 * NB;
    #pragma unroll
    for (int j = 0; j < 32; j += 4) {
      float4 f = *(const float4*)(px + j);
      int nl = bq * 32 + j;
      Bs[nl + 0][ba] = (__bf16)f.x; Bs[nl + 1][ba] = (__bf16)f.y;
      Bs[nl + 2][ba] = (__bf16)f.z; Bs[nl + 3][ba] = (__bf16)f.w;
    }
    __syncthreads();
    #pragma unroll
    for (int kk = 0; kk < 2; ++kk) {
      int ko = kk * 32 + kgrp * 8;
      bf16x8 af[4], bg[4];
      #pragma unroll
      for (int i = 0; i < 4; ++i) af[i] = *(const bf16x8*)&As[wr * 64 + i * 16 + rrow][ko];
      #pragma unroll
      for (int j = 0; j < 4; ++j) bg[j] = *(const bf16x8*)&Bs[wc * 64 + j * 16 + rrow][ko];
      #pragma unroll
      for (int i = 0; i < 4; ++i)
        #pragma unroll
        for (int j = 0; j < 4; ++j)
          acc[i][j] = __builtin_amdgcn_mfma_f32_16x16x32_bf16(af[i], bg[j], acc[i][j], 0, 0, 0);
    }
    __syncthreads();
  }
  float* ob = out + (size_t)b * CB * NB;
  #pragma unroll
  for (int i = 0; i < 4; ++i)
    #pragma unroll
    for (int rr = 0; rr < 4; ++rr) {
      int row = tr * 128 + wr * 64 + i * 16 + kgrp * 4 + rr;
      float ev = evec[b * CB + row];
      #pragma unroll
      for (int j = 0; j < 4; ++j) {
        int col = tn * 128 + wc * 64 + j * 16 + rrow;
        ob[(size_t)row * NB + col] = acc[i][j][rr] + ev;
      }
    }
}

extern "C" void kernel_launch(void* const* d_in, const int* in_sizes, int n_in,
                              void* d_out, int out_size, void* d_ws, size_t ws_size,
                              hipStream_t stream) {
  const float* x  = (const float*)d_in[0];
  const float* w1 = (const float*)d_in[1];
  const float* b1 = (const float*)d_in[2];
  const float* w2 = (const float*)d_in[3];
  const float* b2 = (const float*)d_in[4];
  const float* w3 = (const float*)d_in[5];
  const float* b3 = (const float*)d_in[6];
  const float* temp = (const float*)d_in[7];
  float* out = (float*)d_out;

  char* ws = (char*)d_ws;
  float*  xsum = (float*)(ws);                 //      24,576 B
  __bf16* Wc   = (__bf16*)(ws + 24576);        //     589,824 B
  __bf16* Gb   = (__bf16*)(ws + 614400);       //   4,718,592 B
  float*  T    = (float*)(ws + 5332992);       //  18,874,368 B
  __bf16* Fb   = (__bf16*)(ws + 24207360);     //   4,718,592 B
  float*  evec = (float*)(ws + 28925952);      //      24,576 B   (total ~28.95 MB)

  k_xsum<<<dim3(16 * 384), 256, 0, stream>>>(x, xsum);
  k_wcat<<<dim3(288), 256, 0, stream>>>(w1, w2, Wc);
  k_gram<<<dim3(9, 16), 256, 0, stream>>>(x, Gb);
  k_wg<<<dim3(18, 16), 256, 0, stream>>>(Wc, Gb, T);
  k_attn<<<dim3(8, 16), 256, 0, stream>>>(w1, b1, w2, b2, w3, b3, temp, xsum, T, Fb, evec);
  k_out<<<dim3(96, 16), 256, 0, stream>>>(Fb, x, evec, out);
}

// Round 2
// 414.718 us; speedup vs baseline: 1.2971x; 1.2971x over previous
//
#include <hip/hip_runtime.h>

// Problem constants: B=16, C=384, H=W=64 -> N=4096, HEADS=8, CH=48.
#define CB 384
#define NB 4096

typedef float f32x4 __attribute__((ext_vector_type(4)));
typedef __bf16 bf16x8 __attribute__((ext_vector_type(8)));

// ---------- helpers ----------
__device__ __forceinline__ void cvt8(const float* __restrict__ src, __bf16* dst) {
  float4 f0 = *(const float4*)src;
  float4 f1 = *(const float4*)(src + 4);
  bf16x8 v = { (__bf16)f0.x, (__bf16)f0.y, (__bf16)f0.z, (__bf16)f0.w,
               (__bf16)f1.x, (__bf16)f1.y, (__bf16)f1.z, (__bf16)f1.w };
  *(bf16x8*)dst = v;
}

// ---------- K0: xsum[b][c] = sum_n x[b][c][n] ----------
__global__ __launch_bounds__(256) void k_xsum(const float* __restrict__ x, float* __restrict__ xsum) {
  const float4* r4 = (const float4*)(x + (size_t)blockIdx.x * NB);
  float s = 0.f;
  for (int j = threadIdx.x; j < NB / 4; j += 256) { float4 f = r4[j]; s += (f.x + f.y) + (f.z + f.w); }
  #pragma unroll
  for (int off = 32; off > 0; off >>= 1) s += __shfl_down(s, off);
  __shared__ float wsum[4];
  if ((threadIdx.x & 63) == 0) wsum[threadIdx.x >> 6] = s;
  __syncthreads();
  if (threadIdx.x == 0) xsum[blockIdx.x] = (wsum[0] + wsum[1]) + (wsum[2] + wsum[3]);
}

// ---------- K0b: Wcat(bf16) = [w1; w2]  (768 x 384) ----------
__global__ __launch_bounds__(256) void k_wcat(const float* __restrict__ w1, const float* __restrict__ w2,
                                              __bf16* __restrict__ Wc) {
  int i = blockIdx.x * 256 + threadIdx.x;
  float4 f = (i < 36864) ? ((const float4*)w1)[i] : ((const float4*)w2)[i - 36864];
  __bf16* d = Wc + (size_t)i * 4;
  d[0] = (__bf16)f.x; d[1] = (__bf16)f.y; d[2] = (__bf16)f.z; d[3] = (__bf16)f.w;
}

// ---------- K1a: split-K Gram partials ----------
// grid (6, NSPLIT, 16): t = upper-tri tile id, s = K-chunk, b = batch
// Gpart[s][b][t][128][128] fp32
__global__ __launch_bounds__(256) void k_gram_part(const float* __restrict__ x, float* __restrict__ Gpart,
                                                   int chunk) {
  const int TRm[6] = {0, 0, 0, 1, 1, 2};
  const int TCm[6] = {0, 1, 2, 1, 2, 2};
  int t = blockIdx.x, s = blockIdx.y, b = blockIdx.z;
  int tr = TRm[t], tc = TCm[t];
  bool diag = (tr == tc);
  const float* xb = x + (size_t)b * CB * NB;
  __shared__ __align__(16) __bf16 As[128][72];
  __shared__ __align__(16) __bf16 Bs[128][72];
  int tid = threadIdx.x, lane = tid & 63;
  int wr = (tid >> 6) >> 1, wc = (tid >> 6) & 1;
  int rrow = lane & 15, kgrp = lane >> 4;
  f32x4 zero = {0.f, 0.f, 0.f, 0.f};
  f32x4 acc[4][4];
  #pragma unroll
  for (int i = 0; i < 4; ++i)
    #pragma unroll
    for (int j = 0; j < 4; ++j) acc[i][j] = zero;
  int sr = tid >> 1, sh = (tid & 1) * 32;
  const float* pa = xb + (size_t)(tr * 128 + sr) * NB + sh;
  const float* pb = xb + (size_t)(tc * 128 + sr) * NB + sh;
  int kbeg = s * chunk, kend = kbeg + chunk;
  for (int k0 = kbeg; k0 < kend; k0 += 64) {
    #pragma unroll
    for (int j = 0; j < 4; ++j) cvt8(pa + k0 + j * 8, &As[sr][sh + j * 8]);
    if (!diag) {
      #pragma unroll
      for (int j = 0; j < 4; ++j) cvt8(pb + k0 + j * 8, &Bs[sr][sh + j * 8]);
    }
    __syncthreads();
    const __bf16 (*Bsrc)[72] = diag ? As : Bs;
    #pragma unroll
    for (int kk = 0; kk < 2; ++kk) {
      int ko = kk * 32 + kgrp * 8;
      bf16x8 af[4], bg[4];
      #pragma unroll
      for (int i = 0; i < 4; ++i) af[i] = *(const bf16x8*)&As[wr * 64 + i * 16 + rrow][ko];
      #pragma unroll
      for (int j = 0; j < 4; ++j) bg[j] = *(const bf16x8*)&Bsrc[wc * 64 + j * 16 + rrow][ko];
      #pragma unroll
      for (int i = 0; i < 4; ++i)
        #pragma unroll
        for (int j = 0; j < 4; ++j)
          acc[i][j] = __builtin_amdgcn_mfma_f32_16x16x32_bf16(af[i], bg[j], acc[i][j], 0, 0, 0);
    }
    __syncthreads();
  }
  float* gp = Gpart + (((size_t)s * 16 + b) * 6 + t) * 16384;
  #pragma unroll
  for (int i = 0; i < 4; ++i)
    #pragma unroll
    for (int rr = 0; rr < 4; ++rr) {
      int row = wr * 64 + i * 16 + kgrp * 4 + rr;
      #pragma unroll
      for (int j = 0; j < 4; ++j) {
        int col = wc * 64 + j * 16 + rrow;
        gp[(size_t)row * 128 + col] = acc[i][j][rr];
      }
    }
}

// ---------- K1b: reduce partials -> Gb(bf16), mirror off-diag tiles ----------
// grid (384, 16)
__global__ __launch_bounds__(256) void k_gsum(const float* __restrict__ Gpart, __bf16* __restrict__ Gb,
                                              int nsplit) {
  const int TRm[6] = {0, 0, 0, 1, 1, 2};
  const int TCm[6] = {0, 1, 2, 1, 2, 2};
  int b = blockIdx.y;
  int idx = blockIdx.x * 256 + threadIdx.x;  // [0, 98304)
  int t = idx / 16384, ij = idx & 16383;
  int i = ij >> 7, j = ij & 127;
  float s = 0.f;
  #pragma unroll 8
  for (int si = 0; si < nsplit; ++si)
    s += Gpart[(((size_t)si * 16 + b) * 6 + t) * 16384 + ij];
  int r = TRm[t] * 128 + i, c = TCm[t] * 128 + j;
  __bf16 v = (__bf16)s;
  Gb[((size_t)b * CB + r) * CB + c] = v;
  if (TRm[t] != TCm[t]) Gb[((size_t)b * CB + c) * CB + r] = v;
}

// ---------- K2: T_b = Wcat(bf16) @ G_b(bf16)  -> fp32 [768][384] ----------
__global__ __launch_bounds__(256) void k_wg(const __bf16* __restrict__ Wc, const __bf16* __restrict__ Gb,
                                            float* __restrict__ T) {
  int b = blockIdx.y;
  int tr = blockIdx.x / 3, tc = blockIdx.x % 3;
  __shared__ __align__(16) __bf16 As[128][72];
  __shared__ __align__(16) __bf16 Bs[128][72];
  int tid = threadIdx.x, lane = tid & 63;
  int wr = (tid >> 6) >> 1, wc = (tid >> 6) & 1;
  int rrow = lane & 15, kgrp = lane >> 4;
  f32x4 zero = {0.f, 0.f, 0.f, 0.f};
  f32x4 acc[4][4];
  #pragma unroll
  for (int i = 0; i < 4; ++i)
    #pragma unroll
    for (int j = 0; j < 4; ++j) acc[i][j] = zero;
  int sr = tid >> 1, sh = (tid & 1) * 32;
  const __bf16* pa = Wc + (size_t)(tr * 128 + sr) * CB + sh;
  const __bf16* pb = Gb + (size_t)b * CB * CB + (size_t)(tc * 128 + sr) * CB + sh;
  for (int k0 = 0; k0 < CB; k0 += 64) {
    #pragma unroll
    for (int j = 0; j < 4; ++j) {
      *(bf16x8*)&As[sr][sh + j * 8] = *(const bf16x8*)(pa + k0 + j * 8);
      *(bf16x8*)&Bs[sr][sh + j * 8] = *(const bf16x8*)(pb + k0 + j * 8);
    }
    __syncthreads();
    #pragma unroll
    for (int kk = 0; kk < 2; ++kk) {
      int ko = kk * 32 + kgrp * 8;
      bf16x8 af[4], bg[4];
      #pragma unroll
      for (int i = 0; i < 4; ++i) af[i] = *(const bf16x8*)&As[wr * 64 + i * 16 + rrow][ko];
      #pragma unroll
      for (int j = 0; j < 4; ++j) bg[j] = *(const bf16x8*)&Bs[wc * 64 + j * 16 + rrow][ko];
      #pragma unroll
      for (int i = 0; i < 4; ++i)
        #pragma unroll
        for (int j = 0; j < 4; ++j)
          acc[i][j] = __builtin_amdgcn_mfma_f32_16x16x32_bf16(af[i], bg[j], acc[i][j], 0, 0, 0);
    }
    __syncthreads();
  }
  float* tb = T + (size_t)b * 768 * CB;
  #pragma unroll
  for (int i = 0; i < 4; ++i)
    #pragma unroll
    for (int rr = 0; rr < 4; ++rr) {
      int row = tr * 128 + wr * 64 + i * 16 + kgrp * 4 + rr;
      #pragma unroll
      for (int j = 0; j < 4; ++j) {
        int col = tc * 128 + wc * 64 + j * 16 + rrow;
        tb[(size_t)row * CB + col] = acc[i][j][rr];
      }
    }
}

// ---------- K3: per (b,h) attention algebra -> attn probs (Aw), evec ----------
// grid (8, 16)
__global__ __launch_bounds__(256) void k_attn(
    const float* __restrict__ w1, const float* __restrict__ b1,
    const float* __restrict__ w2, const float* __restrict__ b2,
    const float* __restrict__ b3,
    const float* __restrict__ temp, const float* __restrict__ xsum,
    const float* __restrict__ w2full, const float* __restrict__ T,
    float* __restrict__ Aw, float* __restrict__ evec) {
  int b = blockIdx.y, h = blockIdx.x, tid = threadIdx.x;
  int c0 = h * 48;
  __shared__ float xsuml[384];
  __shared__ float cA[48][133];
  __shared__ float cB[48][133];
  __shared__ float Sl[48][49];
  __shared__ float nq[48], nk[48], wx1[48], wx2[48];

  for (int i = tid; i < 384; i += 256) xsuml[i] = xsum[b * CB + i];
  __syncthreads();

  // phase 1 (all 256 threads, 16 lanes per row): s1 = W.row . xsum, s2 = T.row . W.row
  for (int base = 0; base < 96; base += 16) {
    int rr = base + (tid >> 4);      // 0..95
    int lg = tid & 15;
    int r = rr % 48;
    bool isq = rr < 48;
    const float* wrow = (isq ? w1 : w2) + (size_t)(c0 + r) * CB;
    const float* trow = T + ((size_t)b * 768 + (isq ? 0 : 384) + c0 + r) * CB;
    float s1 = 0.f, s2 = 0.f;
    for (int e = lg; e < CB; e += 16) { float w = wrow[e]; s1 += w * xsuml[e]; s2 += w * trow[e]; }
    #pragma unroll
    for (int off = 8; off > 0; off >>= 1) {
      s1 += __shfl_xor(s1, off, 16);
      s2 += __shfl_xor(s2, off, 16);
    }
    if (lg == 0) {
      float bb = (isq ? b1 : b2)[c0 + r];
      float n2 = s2 + 2.f * bb * s1 + 4096.f * bb * bb;
      float nv = fmaxf(sqrtf(fmaxf(n2, 0.f)), 1e-12f);
      if (isq) { wx1[r] = s1; nq[r] = nv; } else { wx2[r] = s1; nk[r] = nv; }
    }
  }
  __syncthreads();

  // phase 2: S = T1 @ W2_h^T, chunked over e
  float sacc[12];
  #pragma unroll
  for (int i = 0; i < 12; ++i) sacc[i] = 0.f;
  int cc = tid % 48, dq = tid / 48;
  for (int ch = 0; ch < 3; ++ch) {
    for (int idx = tid; idx < 1536; idx += 256) {
      int row = idx >> 5, q4 = (idx & 31) * 4;
      float4 fa = *(const float4*)(T + ((size_t)b * 768 + c0 + row) * CB + ch * 128 + q4);
      float4 fw = *(const float4*)(w2full + (size_t)(c0 + row) * CB + ch * 128 + q4);
      cA[row][q4 + 0] = fa.x; cA[row][q4 + 1] = fa.y; cA[row][q4 + 2] = fa.z; cA[row][q4 + 3] = fa.w;
      cB[row][q4 + 0] = fw.x; cB[row][q4 + 1] = fw.y; cB[row][q4 + 2] = fw.z; cB[row][q4 + 3] = fw.w;
    }
    __syncthreads();
    if (tid < 192) {
      for (int e = 0; e < 128; ++e) {
        float av = cA[cc][e];
        #pragma unroll
        for (int i = 0; i < 12; ++i) sacc[i] += av * cB[dq * 12 + i][e];
      }
    }
    __syncthreads();
  }
  if (tid < 192) {
    float b1c = b1[c0 + cc];
    float th = temp[h];
    #pragma unroll
    for (int i = 0; i < 12; ++i) {
      int d = dq * 12 + i;
      float b2d = b2[c0 + d];
      float sraw = sacc[i] + b1c * wx2[d] + b2d * wx1[cc] + 4096.f * b1c * b2d;
      Sl[cc][d] = th * sraw / (nq[cc] * nk[d]);
    }
  }
  __syncthreads();

  // phase 3: softmax rows + evec + write attn probs
  if (tid < 48) {
    float m = -1e30f;
    #pragma unroll 4
    for (int d = 0; d < 48; ++d) m = fmaxf(m, Sl[tid][d]);
    float ssum = 0.f;
    #pragma unroll 4
    for (int d = 0; d < 48; ++d) { float p = __expf(Sl[tid][d] - m); Sl[tid][d] = p; ssum += p; }
    float inv = 1.f / ssum;
    float ev = 0.f;
    float* arow = Aw + (((size_t)b * 8 + h) * 48 + tid) * 48;
    #pragma unroll 4
    for (int d = 0; d < 48; ++d) {
      float a_ = Sl[tid][d] * inv;
      arow[d] = a_;
      ev += a_ * b3[c0 + d];
    }
    evec[b * CB + c0 + tid] = b3[c0 + tid] + ev;
  }
}

// ---------- K3b: F rows: F[c] = W3[c0+c] + attn[c] @ W3_head + I  -> bf16 ----------
// grid (3, 8, 16): ch chunk of 128 cols, h, b
__global__ __launch_bounds__(256) void k_fb(const float* __restrict__ w3, const float* __restrict__ Aw,
                                            __bf16* __restrict__ Fb) {
  int ch = blockIdx.x, h = blockIdx.y, b = blockIdx.z;
  int c0 = h * 48, tid = threadIdx.x;
  __shared__ float a_s[48][49];
  __shared__ float w_s[48][129];
  const float* ab = Aw + ((size_t)b * 8 + h) * 2304;
  for (int idx = tid; idx < 2304; idx += 256) a_s[idx / 48][idx % 48] = ab[idx];
  for (int idx = tid; idx < 1536; idx += 256) {
    int row = idx >> 5, q4 = (idx & 31) * 4;
    float4 fw = *(const float4*)(w3 + (size_t)(c0 + row) * CB + ch * 128 + q4);
    w_s[row][q4 + 0] = fw.x; w_s[row][q4 + 1] = fw.y; w_s[row][q4 + 2] = fw.z; w_s[row][q4 + 3] = fw.w;
  }
  __syncthreads();
  for (int idx = tid; idx < 6144; idx += 256) {
    int c = idx >> 7, a = idx & 127;
    float acc = w_s[c][a];
    #pragma unroll 8
    for (int d = 0; d < 48; ++d) acc += a_s[c][d] * w_s[d][a];
    int ga = ch * 128 + a;
    float val = acc + ((ga == c0 + c) ? 1.f : 0.f);
    Fb[((size_t)b * CB + c0 + c) * CB + ga] = (__bf16)val;
  }
}

// ---------- K4: out_b = F_b @ x_b + e_b ----------
// grid (96, 16): blockIdx.x = tn*3 + tr
__global__ __launch_bounds__(256) void k_out(const __bf16* __restrict__ Fb, const float* __restrict__ x,
                                             const float* __restrict__ evec, float* __restrict__ out) {
  int b = blockIdx.y;
  int tr = blockIdx.x % 3, tn = blockIdx.x / 3;
  __shared__ __align__(16) __bf16 As[128][72];
  __shared__ __align__(16) __bf16 Bs[128][72];  // [n_local][k]
  int tid = threadIdx.x, lane = tid & 63;
  int wr = (tid >> 6) >> 1, wc = (tid >> 6) & 1;
  int rrow = lane & 15, kgrp = lane >> 4;
  f32x4 zero = {0.f, 0.f, 0.f, 0.f};
  f32x4 acc[4][4];
  #pragma unroll
  for (int i = 0; i < 4; ++i)
    #pragma unroll
    for (int j = 0; j < 4; ++j) acc[i][j] = zero;
  int sr = tid >> 1, sh = (tid & 1) * 32;
  const __bf16* pa = Fb + ((size_t)b * CB + tr * 128 + sr) * CB + sh;
  int ba = tid >> 2, bq = tid & 3;
  const float* pxbase = x + ((size_t)b * CB + ba) * NB + tn * 128 + bq * 32;
  for (int k0 = 0; k0 < CB; k0 += 64) {
    #pragma unroll
    for (int j = 0; j < 4; ++j)
      *(bf16x8*)&As[sr][sh + j * 8] = *(const bf16x8*)(pa + k0 + j * 8);
    const float* px = pxbase + (size_t)k0 * NB;
    #pragma unroll
    for (int j = 0; j < 32; j += 4) {
      float4 f = *(const float4*)(px + j);
      int nl = bq * 32 + j;
      Bs[nl + 0][ba] = (__bf16)f.x; Bs[nl + 1][ba] = (__bf16)f.y;
      Bs[nl + 2][ba] = (__bf16)f.z; Bs[nl + 3][ba] = (__bf16)f.w;
    }
    __syncthreads();
    #pragma unroll
    for (int kk = 0; kk < 2; ++kk) {
      int ko = kk * 32 + kgrp * 8;
      bf16x8 af[4], bg[4];
      #pragma unroll
      for (int i = 0; i < 4; ++i) af[i] = *(const bf16x8*)&As[wr * 64 + i * 16 + rrow][ko];
      #pragma unroll
      for (int j = 0; j < 4; ++j) bg[j] = *(const bf16x8*)&Bs[wc * 64 + j * 16 + rrow][ko];
      #pragma unroll
      for (int i = 0; i < 4; ++i)
        #pragma unroll
        for (int j = 0; j < 4; ++j)
          acc[i][j] = __builtin_amdgcn_mfma_f32_16x16x32_bf16(af[i], bg[j], acc[i][j], 0, 0, 0);
    }
    __syncthreads();
  }
  float* ob = out + (size_t)b * CB * NB;
  #pragma unroll
  for (int i = 0; i < 4; ++i)
    #pragma unroll
    for (int rr = 0; rr < 4; ++rr) {
      int row = tr * 128 + wr * 64 + i * 16 + kgrp * 4 + rr;
      float ev = evec[b * CB + row];
      #pragma unroll
      for (int j = 0; j < 4; ++j) {
        int col = tn * 128 + wc * 64 + j * 16 + rrow;
        ob[(size_t)row * NB + col] = acc[i][j][rr] + ev;
      }
    }
}

extern "C" void kernel_launch(void* const* d_in, const int* in_sizes, int n_in,
                              void* d_out, int out_size, void* d_ws, size_t ws_size,
                              hipStream_t stream) {
  const float* x  = (const float*)d_in[0];
  const float* w1 = (const float*)d_in[1];
  const float* b1 = (const float*)d_in[2];
  const float* w2 = (const float*)d_in[3];
  const float* b2 = (const float*)d_in[4];
  const float* w3 = (const float*)d_in[5];
  const float* b3 = (const float*)d_in[6];
  const float* temp = (const float*)d_in[7];
  float* out = (float*)d_out;

  char* ws = (char*)d_ws;
  float*  xsum  = (float*)(ws);                 // 24,576
  __bf16* Wc    = (__bf16*)(ws + 24576);        // 589,824
  __bf16* Gb    = (__bf16*)(ws + 614400);       // 4,718,592
  float*  T     = (float*)(ws + 5332992);       // 18,874,368
  __bf16* Fb    = (__bf16*)(ws + 24207360);     // 4,718,592
  float*  evec  = (float*)(ws + 28925952);      // 24,576
  float*  Aw    = (float*)(ws + 28950528);      // 1,179,648
  float*  Gpart = (float*)(ws + 30130176);      // nsplit * 6,291,456

  const size_t base = 30130176;
  int nsplit = 1;
  if (base + 8ull * 6291456 <= ws_size) nsplit = 8;
  else if (base + 4ull * 6291456 <= ws_size) nsplit = 4;
  else if (base + 2ull * 6291456 <= ws_size) nsplit = 2;

  k_xsum<<<dim3(16 * 384), 256, 0, stream>>>(x, xsum);
  k_wcat<<<dim3(288), 256, 0, stream>>>(w1, w2, Wc);
  k_gram_part<<<dim3(6, nsplit, 16), 256, 0, stream>>>(x, Gpart, NB / nsplit);
  k_gsum<<<dim3(384, 16), 256, 0, stream>>>(Gpart, Gb, nsplit);
  k_wg<<<dim3(18, 16), 256, 0, stream>>>(Wc, Gb, T);
  k_attn<<<dim3(8, 16), 256, 0, stream>>>(w1, b1, w2, b2, b3, temp, xsum, w2, T, Aw, evec);
  k_fb<<<dim3(3, 8, 16), 256, 0, stream>>>(w3, Aw, Fb);
  k_out<<<dim3(96, 16), 256, 0, stream>>>(Fb, x, evec, out);
}

// Round 3
// 389.963 us; speedup vs baseline: 1.3795x; 1.0635x over previous
//
#include <hip/hip_runtime.h>

// Problem constants: B=16, C=384, H=W=64 -> N=4096, HEADS=8, CH=48.
#define CB 384
#define NB 4096

typedef float f32x4 __attribute__((ext_vector_type(4)));
typedef __bf16 bf16x8 __attribute__((ext_vector_type(8)));
typedef __bf16 bf16x4 __attribute__((ext_vector_type(4)));

// ---------- helpers ----------
__device__ __forceinline__ void cvt8(const float* __restrict__ src, __bf16* dst) {
  float4 f0 = *(const float4*)src;
  float4 f1 = *(const float4*)(src + 4);
  bf16x8 v = { (__bf16)f0.x, (__bf16)f0.y, (__bf16)f0.z, (__bf16)f0.w,
               (__bf16)f1.x, (__bf16)f1.y, (__bf16)f1.z, (__bf16)f1.w };
  *(bf16x8*)dst = v;
}

// ---------- K0 (fast): x -> xbf [c][n], xbfT [n][c], xsum (atomic) ----------
// grid (6, 16, 16): ct, nt, b.  Tile: 64 c x 256 n.
#define XT_PITCH 264
__global__ __launch_bounds__(256) void k_xbf(const float* __restrict__ x, __bf16* __restrict__ xbf,
                                             __bf16* __restrict__ xbfT, float* __restrict__ xsum) {
  int ct = blockIdx.x, nt = blockIdx.y, b = blockIdx.z;
  int c0 = ct * 64, n0 = nt * 256;
  __shared__ __bf16 tile[64][XT_PITCH];
  const float* xb = x + ((size_t)b * CB + c0) * NB + n0;
  __bf16* yb = xbf + ((size_t)b * CB + c0) * NB + n0;
  int t = threadIdx.x;
  // phase 1: fp32 read (coalesced) -> bf16 global + LDS tile
  #pragma unroll
  for (int j = 0; j < 16; ++j) {
    int i = t + 256 * j;            // float4 index in 64x256 tile
    int r = i >> 6, c4 = (i & 63) * 4;
    float4 f = *(const float4*)(xb + (size_t)r * NB + c4);
    bf16x4 v = { (__bf16)f.x, (__bf16)f.y, (__bf16)f.z, (__bf16)f.w };
    *(bf16x4*)(yb + (size_t)r * NB + c4) = v;
    *(bf16x4*)&tile[r][c4] = v;
  }
  __syncthreads();
  // phase 2: row sums -> atomicAdd
  {
    int row = t >> 2, q = t & 3;
    float s = 0.f;
    #pragma unroll 8
    for (int m = 0; m < 64; ++m) s += (float)tile[row][q * 64 + m];
    s += __shfl_xor(s, 1, 4);
    s += __shfl_xor(s, 2, 4);
    if (q == 0) atomicAdd(&xsum[b * CB + c0 + row], s);
  }
  // phase 3: transposed write xbfT[n][c]
  __bf16* zb = xbfT + ((size_t)b * NB + n0 + t) * CB + c0;
  #pragma unroll
  for (int c8 = 0; c8 < 8; ++c8) {
    bf16x8 v;
    #pragma unroll
    for (int m = 0; m < 8; ++m) v[m] = tile[c8 * 8 + m][t];
    *(bf16x8*)(zb + c8 * 8) = v;
  }
}

// ---------- K0 (fallback): xsum only ----------
__global__ __launch_bounds__(256) void k_xsum(const float* __restrict__ x, float* __restrict__ xsum) {
  const float4* r4 = (const float4*)(x + (size_t)blockIdx.x * NB);
  float s = 0.f;
  for (int j = threadIdx.x; j < NB / 4; j += 256) { float4 f = r4[j]; s += (f.x + f.y) + (f.z + f.w); }
  #pragma unroll
  for (int off = 32; off > 0; off >>= 1) s += __shfl_down(s, off);
  __shared__ float wsum[4];
  if ((threadIdx.x & 63) == 0) wsum[threadIdx.x >> 6] = s;
  __syncthreads();
  if (threadIdx.x == 0) xsum[blockIdx.x] = (wsum[0] + wsum[1]) + (wsum[2] + wsum[3]);
}

// ---------- K0b: Wcat(bf16) = [w1; w2]  (768 x 384) ----------
__global__ __launch_bounds__(256) void k_wcat(const float* __restrict__ w1, const float* __restrict__ w2,
                                              __bf16* __restrict__ Wc) {
  int i = blockIdx.x * 256 + threadIdx.x;
  float4 f = (i < 36864) ? ((const float4*)w1)[i] : ((const float4*)w2)[i - 36864];
  __bf16* d = Wc + (size_t)i * 4;
  d[0] = (__bf16)f.x; d[1] = (__bf16)f.y; d[2] = (__bf16)f.z; d[3] = (__bf16)f.w;
}

// ---------- K1a (fast): split-K Gram partials from bf16 x ----------
// grid (6, NSPLIT, 16)
__global__ __launch_bounds__(256) void k_gram_bf(const __bf16* __restrict__ xbf, float* __restrict__ Gpart,
                                                 int chunk) {
  const int TRm[6] = {0, 0, 0, 1, 1, 2};
  const int TCm[6] = {0, 1, 2, 1, 2, 2};
  int t = blockIdx.x, s = blockIdx.y, b = blockIdx.z;
  int tr = TRm[t], tc = TCm[t];
  bool diag = (tr == tc);
  const __bf16* xb = xbf + (size_t)b * CB * NB;
  __shared__ __align__(16) __bf16 As[128][72];
  __shared__ __align__(16) __bf16 Bs[128][72];
  int tid = threadIdx.x, lane = tid & 63;
  int wr = (tid >> 6) >> 1, wc = (tid >> 6) & 1;
  int rrow = lane & 15, kgrp = lane >> 4;
  f32x4 zero = {0.f, 0.f, 0.f, 0.f};
  f32x4 acc[4][4];
  #pragma unroll
  for (int i = 0; i < 4; ++i)
    #pragma unroll
    for (int j = 0; j < 4; ++j) acc[i][j] = zero;
  int sr = tid >> 1, sh = (tid & 1) * 32;
  const __bf16* pa = xb + (size_t)(tr * 128 + sr) * NB + sh;
  const __bf16* pb = xb + (size_t)(tc * 128 + sr) * NB + sh;
  int kbeg = s * chunk, kend = kbeg + chunk;
  for (int k0 = kbeg; k0 < kend; k0 += 64) {
    #pragma unroll
    for (int j = 0; j < 4; ++j) *(bf16x8*)&As[sr][sh + j * 8] = *(const bf16x8*)(pa + k0 + j * 8);
    if (!diag) {
      #pragma unroll
      for (int j = 0; j < 4; ++j) *(bf16x8*)&Bs[sr][sh + j * 8] = *(const bf16x8*)(pb + k0 + j * 8);
    }
    __syncthreads();
    const __bf16 (*Bsrc)[72] = diag ? As : Bs;
    #pragma unroll
    for (int kk = 0; kk < 2; ++kk) {
      int ko = kk * 32 + kgrp * 8;
      bf16x8 af[4], bg[4];
      #pragma unroll
      for (int i = 0; i < 4; ++i) af[i] = *(const bf16x8*)&As[wr * 64 + i * 16 + rrow][ko];
      #pragma unroll
      for (int j = 0; j < 4; ++j) bg[j] = *(const bf16x8*)&Bsrc[wc * 64 + j * 16 + rrow][ko];
      #pragma unroll
      for (int i = 0; i < 4; ++i)
        #pragma unroll
        for (int j = 0; j < 4; ++j)
          acc[i][j] = __builtin_amdgcn_mfma_f32_16x16x32_bf16(af[i], bg[j], acc[i][j], 0, 0, 0);
    }
    __syncthreads();
  }
  float* gp = Gpart + (((size_t)s * 16 + b) * 6 + t) * 16384;
  #pragma unroll
  for (int i = 0; i < 4; ++i)
    #pragma unroll
    for (int rr = 0; rr < 4; ++rr) {
      int row = wr * 64 + i * 16 + kgrp * 4 + rr;
      #pragma unroll
      for (int j = 0; j < 4; ++j) {
        int col = wc * 64 + j * 16 + rrow;
        gp[(size_t)row * 128 + col] = acc[i][j][rr];
      }
    }
}

// ---------- K1a (fallback): from fp32 x ----------
__global__ __launch_bounds__(256) void k_gram_f32(const float* __restrict__ x, float* __restrict__ Gpart,
                                                  int chunk) {
  const int TRm[6] = {0, 0, 0, 1, 1, 2};
  const int TCm[6] = {0, 1, 2, 1, 2, 2};
  int t = blockIdx.x, s = blockIdx.y, b = blockIdx.z;
  int tr = TRm[t], tc = TCm[t];
  bool diag = (tr == tc);
  const float* xb = x + (size_t)b * CB * NB;
  __shared__ __align__(16) __bf16 As[128][72];
  __shared__ __align__(16) __bf16 Bs[128][72];
  int tid = threadIdx.x, lane = tid & 63;
  int wr = (tid >> 6) >> 1, wc = (tid >> 6) & 1;
  int rrow = lane & 15, kgrp = lane >> 4;
  f32x4 zero = {0.f, 0.f, 0.f, 0.f};
  f32x4 acc[4][4];
  #pragma unroll
  for (int i = 0; i < 4; ++i)
    #pragma unroll
    for (int j = 0; j < 4; ++j) acc[i][j] = zero;
  int sr = tid >> 1, sh = (tid & 1) * 32;
  const float* pa = xb + (size_t)(tr * 128 + sr) * NB + sh;
  const float* pb = xb + (size_t)(tc * 128 + sr) * NB + sh;
  int kbeg = s * chunk, kend = kbeg + chunk;
  for (int k0 = kbeg; k0 < kend; k0 += 64) {
    #pragma unroll
    for (int j = 0; j < 4; ++j) cvt8(pa + k0 + j * 8, &As[sr][sh + j * 8]);
    if (!diag) {
      #pragma unroll
      for (int j = 0; j < 4; ++j) cvt8(pb + k0 + j * 8, &Bs[sr][sh + j * 8]);
    }
    __syncthreads();
    const __bf16 (*Bsrc)[72] = diag ? As : Bs;
    #pragma unroll
    for (int kk = 0; kk < 2; ++kk) {
      int ko = kk * 32 + kgrp * 8;
      bf16x8 af[4], bg[4];
      #pragma unroll
      for (int i = 0; i < 4; ++i) af[i] = *(const bf16x8*)&As[wr * 64 + i * 16 + rrow][ko];
      #pragma unroll
      for (int j = 0; j < 4; ++j) bg[j] = *(const bf16x8*)&Bsrc[wc * 64 + j * 16 + rrow][ko];
      #pragma unroll
      for (int i = 0; i < 4; ++i)
        #pragma unroll
        for (int j = 0; j < 4; ++j)
          acc[i][j] = __builtin_amdgcn_mfma_f32_16x16x32_bf16(af[i], bg[j], acc[i][j], 0, 0, 0);
    }
    __syncthreads();
  }
  float* gp = Gpart + (((size_t)s * 16 + b) * 6 + t) * 16384;
  #pragma unroll
  for (int i = 0; i < 4; ++i)
    #pragma unroll
    for (int rr = 0; rr < 4; ++rr) {
      int row = wr * 64 + i * 16 + kgrp * 4 + rr;
      #pragma unroll
      for (int j = 0; j < 4; ++j) {
        int col = wc * 64 + j * 16 + rrow;
        gp[(size_t)row * 128 + col] = acc[i][j][rr];
      }
    }
}

// ---------- K1b: reduce partials -> Gb(bf16), mirror off-diag ----------
__global__ __launch_bounds__(256) void k_gsum(const float* __restrict__ Gpart, __bf16* __restrict__ Gb,
                                              int nsplit) {
  const int TRm[6] = {0, 0, 0, 1, 1, 2};
  const int TCm[6] = {0, 1, 2, 1, 2, 2};
  int b = blockIdx.y;
  int idx = blockIdx.x * 256 + threadIdx.x;
  int t = idx / 16384, ij = idx & 16383;
  int i = ij >> 7, j = ij & 127;
  float s = 0.f;
  #pragma unroll 8
  for (int si = 0; si < nsplit; ++si)
    s += Gpart[(((size_t)si * 16 + b) * 6 + t) * 16384 + ij];
  int r = TRm[t] * 128 + i, c = TCm[t] * 128 + j;
  __bf16 v = (__bf16)s;
  Gb[((size_t)b * CB + r) * CB + c] = v;
  if (TRm[t] != TCm[t]) Gb[((size_t)b * CB + c) * CB + r] = v;
}

// ---------- K2: T_b = Wcat @ G_b -> fp32 [768][384] ----------
__global__ __launch_bounds__(256) void k_wg(const __bf16* __restrict__ Wc, const __bf16* __restrict__ Gb,
                                            float* __restrict__ T) {
  int b = blockIdx.y;
  int tr = blockIdx.x / 3, tc = blockIdx.x % 3;
  __shared__ __align__(16) __bf16 As[128][72];
  __shared__ __align__(16) __bf16 Bs[128][72];
  int tid = threadIdx.x, lane = tid & 63;
  int wr = (tid >> 6) >> 1, wc = (tid >> 6) & 1;
  int rrow = lane & 15, kgrp = lane >> 4;
  f32x4 zero = {0.f, 0.f, 0.f, 0.f};
  f32x4 acc[4][4];
  #pragma unroll
  for (int i = 0; i < 4; ++i)
    #pragma unroll
    for (int j = 0; j < 4; ++j) acc[i][j] = zero;
  int sr = tid >> 1, sh = (tid & 1) * 32;
  const __bf16* pa = Wc + (size_t)(tr * 128 + sr) * CB + sh;
  const __bf16* pb = Gb + (size_t)b * CB * CB + (size_t)(tc * 128 + sr) * CB + sh;
  for (int k0 = 0; k0 < CB; k0 += 64) {
    #pragma unroll
    for (int j = 0; j < 4; ++j) {
      *(bf16x8*)&As[sr][sh + j * 8] = *(const bf16x8*)(pa + k0 + j * 8);
      *(bf16x8*)&Bs[sr][sh + j * 8] = *(const bf16x8*)(pb + k0 + j * 8);
    }
    __syncthreads();
    #pragma unroll
    for (int kk = 0; kk < 2; ++kk) {
      int ko = kk * 32 + kgrp * 8;
      bf16x8 af[4], bg[4];
      #pragma unroll
      for (int i = 0; i < 4; ++i) af[i] = *(const bf16x8*)&As[wr * 64 + i * 16 + rrow][ko];
      #pragma unroll
      for (int j = 0; j < 4; ++j) bg[j] = *(const bf16x8*)&Bs[wc * 64 + j * 16 + rrow][ko];
      #pragma unroll
      for (int i = 0; i < 4; ++i)
        #pragma unroll
        for (int j = 0; j < 4; ++j)
          acc[i][j] = __builtin_amdgcn_mfma_f32_16x16x32_bf16(af[i], bg[j], acc[i][j], 0, 0, 0);
    }
    __syncthreads();
  }
  float* tb = T + (size_t)b * 768 * CB;
  #pragma unroll
  for (int i = 0; i < 4; ++i)
    #pragma unroll
    for (int rr = 0; rr < 4; ++rr) {
      int row = tr * 128 + wr * 64 + i * 16 + kgrp * 4 + rr;
      #pragma unroll
      for (int j = 0; j < 4; ++j) {
        int col = tc * 128 + wc * 64 + j * 16 + rrow;
        tb[(size_t)row * CB + col] = acc[i][j][rr];
      }
    }
}

// ---------- K3: per (b,h) attention algebra -> attn probs (Aw), evec ----------
__global__ __launch_bounds__(256) void k_attn(
    const float* __restrict__ w1, const float* __restrict__ b1,
    const float* __restrict__ w2, const float* __restrict__ b2,
    const float* __restrict__ b3,
    const float* __restrict__ temp, const float* __restrict__ xsum,
    const float* __restrict__ w2full, const float* __restrict__ T,
    float* __restrict__ Aw, float* __restrict__ evec) {
  int b = blockIdx.y, h = blockIdx.x, tid = threadIdx.x;
  int c0 = h * 48;
  __shared__ float xsuml[384];
  __shared__ float cA[48][133];
  __shared__ float cB[48][133];
  __shared__ float Sl[48][49];
  __shared__ float nq[48], nk[48], wx1[48], wx2[48];

  for (int i = tid; i < 384; i += 256) xsuml[i] = xsum[b * CB + i];
  __syncthreads();

  for (int base = 0; base < 96; base += 16) {
    int rr = base + (tid >> 4);
    int lg = tid & 15;
    int r = rr % 48;
    bool isq = rr < 48;
    const float* wrow = (isq ? w1 : w2) + (size_t)(c0 + r) * CB;
    const float* trow = T + ((size_t)b * 768 + (isq ? 0 : 384) + c0 + r) * CB;
    float s1 = 0.f, s2 = 0.f;
    for (int e = lg; e < CB; e += 16) { float w = wrow[e]; s1 += w * xsuml[e]; s2 += w * trow[e]; }
    #pragma unroll
    for (int off = 8; off > 0; off >>= 1) {
      s1 += __shfl_xor(s1, off, 16);
      s2 += __shfl_xor(s2, off, 16);
    }
    if (lg == 0) {
      float bb = (isq ? b1 : b2)[c0 + r];
      float n2 = s2 + 2.f * bb * s1 + 4096.f * bb * bb;
      float nv = fmaxf(sqrtf(fmaxf(n2, 0.f)), 1e-12f);
      if (isq) { wx1[r] = s1; nq[r] = nv; } else { wx2[r] = s1; nk[r] = nv; }
    }
  }
  __syncthreads();

  float sacc[12];
  #pragma unroll
  for (int i = 0; i < 12; ++i) sacc[i] = 0.f;
  int cc = tid % 48, dq = tid / 48;
  for (int ch = 0; ch < 3; ++ch) {
    for (int idx = tid; idx < 1536; idx += 256) {
      int row = idx >> 5, q4 = (idx & 31) * 4;
      float4 fa = *(const float4*)(T + ((size_t)b * 768 + c0 + row) * CB + ch * 128 + q4);
      float4 fw = *(const float4*)(w2full + (size_t)(c0 + row) * CB + ch * 128 + q4);
      cA[row][q4 + 0] = fa.x; cA[row][q4 + 1] = fa.y; cA[row][q4 + 2] = fa.z; cA[row][q4 + 3] = fa.w;
      cB[row][q4 + 0] = fw.x; cB[row][q4 + 1] = fw.y; cB[row][q4 + 2] = fw.z; cB[row][q4 + 3] = fw.w;
    }
    __syncthreads();
    if (tid < 192) {
      for (int e = 0; e < 128; ++e) {
        float av = cA[cc][e];
        #pragma unroll
        for (int i = 0; i < 12; ++i) sacc[i] += av * cB[dq * 12 + i][e];
      }
    }
    __syncthreads();
  }
  if (tid < 192) {
    float b1c = b1[c0 + cc];
    float th = temp[h];
    #pragma unroll
    for (int i = 0; i < 12; ++i) {
      int d = dq * 12 + i;
      float b2d = b2[c0 + d];
      float sraw = sacc[i] + b1c * wx2[d] + b2d * wx1[cc] + 4096.f * b1c * b2d;
      Sl[cc][d] = th * sraw / (nq[cc] * nk[d]);
    }
  }
  __syncthreads();

  if (tid < 48) {
    float m = -1e30f;
    #pragma unroll 4
    for (int d = 0; d < 48; ++d) m = fmaxf(m, Sl[tid][d]);
    float ssum = 0.f;
    #pragma unroll 4
    for (int d = 0; d < 48; ++d) { float p = __expf(Sl[tid][d] - m); Sl[tid][d] = p; ssum += p; }
    float inv = 1.f / ssum;
    float ev = 0.f;
    float* arow = Aw + (((size_t)b * 8 + h) * 48 + tid) * 48;
    #pragma unroll 4
    for (int d = 0; d < 48; ++d) {
      float a_ = Sl[tid][d] * inv;
      arow[d] = a_;
      ev += a_ * b3[c0 + d];
    }
    evec[b * CB + c0 + tid] = b3[c0 + tid] + ev;
  }
}

// ---------- K3b: F rows -> bf16 ----------
__global__ __launch_bounds__(256) void k_fb(const float* __restrict__ w3, const float* __restrict__ Aw,
                                            __bf16* __restrict__ Fb) {
  int ch = blockIdx.x, h = blockIdx.y, b = blockIdx.z;
  int c0 = h * 48, tid = threadIdx.x;
  __shared__ float a_s[48][49];
  __shared__ float w_s[48][129];
  const float* ab = Aw + ((size_t)b * 8 + h) * 2304;
  for (int idx = tid; idx < 2304; idx += 256) a_s[idx / 48][idx % 48] = ab[idx];
  for (int idx = tid; idx < 1536; idx += 256) {
    int row = idx >> 5, q4 = (idx & 31) * 4;
    float4 fw = *(const float4*)(w3 + (size_t)(c0 + row) * CB + ch * 128 + q4);
    w_s[row][q4 + 0] = fw.x; w_s[row][q4 + 1] = fw.y; w_s[row][q4 + 2] = fw.z; w_s[row][q4 + 3] = fw.w;
  }
  __syncthreads();
  for (int idx = tid; idx < 6144; idx += 256) {
    int c = idx >> 7, a = idx & 127;
    float acc = w_s[c][a];
    #pragma unroll 8
    for (int d = 0; d < 48; ++d) acc += a_s[c][d] * w_s[d][a];
    int ga = ch * 128 + a;
    float val = acc + ((ga == c0 + c) ? 1.f : 0.f);
    Fb[((size_t)b * CB + c0 + c) * CB + ga] = (__bf16)val;
  }
}

// ---------- K4 (fast): out = F @ x + e, B from xbfT (no transpose staging) ----------
// grid (96, 16): blockIdx.x = tn*3 + tr
__global__ __launch_bounds__(256) void k_out_bf(const __bf16* __restrict__ Fb, const __bf16* __restrict__ xbfT,
                                                const float* __restrict__ evec, float* __restrict__ out) {
  int b = blockIdx.y;
  int tr = blockIdx.x % 3, tn = blockIdx.x / 3;
  __shared__ __align__(16) __bf16 As[128][72];
  __shared__ __align__(16) __bf16 Bs[128][72];  // [n_local][k]
  int tid = threadIdx.x, lane = tid & 63;
  int wr = (tid >> 6) >> 1, wc = (tid >> 6) & 1;
  int rrow = lane & 15, kgrp = lane >> 4;
  f32x4 zero = {0.f, 0.f, 0.f, 0.f};
  f32x4 acc[4][4];
  #pragma unroll
  for (int i = 0; i < 4; ++i)
    #pragma unroll
    for (int j = 0; j < 4; ++j) acc[i][j] = zero;
  int sr = tid >> 1, sh = (tid & 1) * 32;
  const __bf16* pa = Fb + ((size_t)b * CB + tr * 128 + sr) * CB + sh;
  const __bf16* pb = xbfT + ((size_t)b * NB + tn * 128 + sr) * CB + sh;
  for (int k0 = 0; k0 < CB; k0 += 64) {
    #pragma unroll
    for (int j = 0; j < 4; ++j) {
      *(bf16x8*)&As[sr][sh + j * 8] = *(const bf16x8*)(pa + k0 + j * 8);
      *(bf16x8*)&Bs[sr][sh + j * 8] = *(const bf16x8*)(pb + k0 + j * 8);
    }
    __syncthreads();
    #pragma unroll
    for (int kk = 0; kk < 2; ++kk) {
      int ko = kk * 32 + kgrp * 8;
      bf16x8 af[4], bg[4];
      #pragma unroll
      for (int i = 0; i < 4; ++i) af[i] = *(const bf16x8*)&As[wr * 64 + i * 16 + rrow][ko];
      #pragma unroll
      for (int j = 0; j < 4; ++j) bg[j] = *(const bf16x8*)&Bs[wc * 64 + j * 16 + rrow][ko];
      #pragma unroll
      for (int i = 0; i < 4; ++i)
        #pragma unroll
        for (int j = 0; j < 4; ++j)
          acc[i][j] = __builtin_amdgcn_mfma_f32_16x16x32_bf16(af[i], bg[j], acc[i][j], 0, 0, 0);
    }
    __syncthreads();
  }
  float* ob = out + (size_t)b * CB * NB;
  #pragma unroll
  for (int i = 0; i < 4; ++i)
    #pragma unroll
    for (int rr = 0; rr < 4; ++rr) {
      int row = tr * 128 + wr * 64 + i * 16 + kgrp * 4 + rr;
      float ev = evec[b * CB + row];
      #pragma unroll
      for (int j = 0; j < 4; ++j) {
        int col = tn * 128 + wc * 64 + j * 16 + rrow;
        ob[(size_t)row * NB + col] = acc[i][j][rr] + ev;
      }
    }
}

// ---------- K4 (fallback): B staged from fp32 x with transpose ----------
__global__ __launch_bounds__(256) void k_out_f32(const __bf16* __restrict__ Fb, const float* __restrict__ x,
                                                 const float* __restrict__ evec, float* __restrict__ out) {
  int b = blockIdx.y;
  int tr = blockIdx.x % 3, tn = blockIdx.x / 3;
  __shared__ __align__(16) __bf16 As[128][72];
  __shared__ __align__(16) __bf16 Bs[128][72];
  int tid = threadIdx.x, lane = tid & 63;
  int wr = (tid >> 6) >> 1, wc = (tid >> 6) & 1;
  int rrow = lane & 15, kgrp = lane >> 4;
  f32x4 zero = {0.f, 0.f, 0.f, 0.f};
  f32x4 acc[4][4];
  #pragma unroll
  for (int i = 0; i < 4; ++i)
    #pragma unroll
    for (int j = 0; j < 4; ++j) acc[i][j] = zero;
  int sr = tid >> 1, sh = (tid & 1) * 32;
  const __bf16* pa = Fb + ((size_t)b * CB + tr * 128 + sr) * CB + sh;
  int ba = tid >> 2, bq = tid & 3;
  const float* pxbase = x + ((size_t)b * CB + ba) * NB + tn * 128 + bq * 32;
  for (int k0 = 0; k0 < CB; k0 += 64) {
    #pragma unroll
    for (int j = 0; j < 4; ++j)
      *(bf16x8*)&As[sr][sh + j * 8] = *(const bf16x8*)(pa + k0 + j * 8);
    const float* px = pxbase + (size_t)k0 * NB;
    #pragma unroll
    for (int j = 0; j < 32; j += 4) {
      float4 f = *(const float4*)(px + j);
      int nl = bq * 32 + j;
      Bs[nl + 0][ba] = (__bf16)f.x; Bs[nl + 1][ba] = (__bf16)f.y;
      Bs[nl + 2][ba] = (__bf16)f.z; Bs[nl + 3][ba] = (__bf16)f.w;
    }
    __syncthreads();
    #pragma unroll
    for (int kk = 0; kk < 2; ++kk) {
      int ko = kk * 32 + kgrp * 8;
      bf16x8 af[4], bg[4];
      #pragma unroll
      for (int i = 0; i < 4; ++i) af[i] = *(const bf16x8*)&As[wr * 64 + i * 16 + rrow][ko];
      #pragma unroll
      for (int j = 0; j < 4; ++j) bg[j] = *(const bf16x8*)&Bs[wc * 64 + j * 16 + rrow][ko];
      #pragma unroll
      for (int i = 0; i < 4; ++i)
        #pragma unroll
        for (int j = 0; j < 4; ++j)
          acc[i][j] = __builtin_amdgcn_mfma_f32_16x16x32_bf16(af[i], bg[j], acc[i][j], 0, 0, 0);
    }
    __syncthreads();
  }
  float* ob = out + (size_t)b * CB * NB;
  #pragma unroll
  for (int i = 0; i < 4; ++i)
    #pragma unroll
    for (int rr = 0; rr < 4; ++rr) {
      int row = tr * 128 + wr * 64 + i * 16 + kgrp * 4 + rr;
      float ev = evec[b * CB + row];
      #pragma unroll
      for (int j = 0; j < 4; ++j) {
        int col = tn * 128 + wc * 64 + j * 16 + rrow;
        ob[(size_t)row * NB + col] = acc[i][j][rr] + ev;
      }
    }
}

extern "C" void kernel_launch(void* const* d_in, const int* in_sizes, int n_in,
                              void* d_out, int out_size, void* d_ws, size_t ws_size,
                              hipStream_t stream) {
  const float* x  = (const float*)d_in[0];
  const float* w1 = (const float*)d_in[1];
  const float* b1 = (const float*)d_in[2];
  const float* w2 = (const float*)d_in[3];
  const float* b2 = (const float*)d_in[4];
  const float* w3 = (const float*)d_in[5];
  const float* b3 = (const float*)d_in[6];
  const float* temp = (const float*)d_in[7];
  float* out = (float*)d_out;

  char* ws = (char*)d_ws;
  float*  xsum = (float*)(ws);                 // 24,576
  __bf16* Wc   = (__bf16*)(ws + 24576);        // 589,824
  __bf16* Gb   = (__bf16*)(ws + 614400);       // 4,718,592
  float*  T    = (float*)(ws + 5332992);       // 18,874,368
  __bf16* Fb   = (__bf16*)(ws + 24207360);     // 4,718,592
  float*  evec = (float*)(ws + 28925952);      // 24,576
  float*  Aw   = (float*)(ws + 28950528);      // 1,179,648  -> ends 30,130,176

  const size_t base = 30130176ull;
  const size_t XBF_BYTES = 50331648ull;   // 16*384*4096*2
  const size_t GP1 = 6291456ull;          // one split of Gpart

  // fast path layout: xbf @ base, xbfT @ base+XBF, Gpart @ base+2*XBF
  __bf16* xbf  = (__bf16*)(ws + base);
  __bf16* xbfT = (__bf16*)(ws + base + XBF_BYTES);
  float*  GpF  = (float*)(ws + base + 2 * XBF_BYTES);

  int nsplit_fast = 0;
  size_t fbase = base + 2 * XBF_BYTES;
  if (fbase + 8 * GP1 <= ws_size) nsplit_fast = 8;
  else if (fbase + 4 * GP1 <= ws_size) nsplit_fast = 4;
  else if (fbase + 2 * GP1 <= ws_size) nsplit_fast = 2;
  else if (fbase + 1 * GP1 <= ws_size) nsplit_fast = 1;

  if (nsplit_fast > 0) {
    hipMemsetAsync(xsum, 0, 24576, stream);
    k_xbf<<<dim3(6, 16, 16), 256, 0, stream>>>(x, xbf, xbfT, xsum);
    k_wcat<<<dim3(288), 256, 0, stream>>>(w1, w2, Wc);
    k_gram_bf<<<dim3(6, nsplit_fast, 16), 256, 0, stream>>>(xbf, GpF, NB / nsplit_fast);
    k_gsum<<<dim3(384, 16), 256, 0, stream>>>(GpF, Gb, nsplit_fast);
    k_wg<<<dim3(18, 16), 256, 0, stream>>>(Wc, Gb, T);
    k_attn<<<dim3(8, 16), 256, 0, stream>>>(w1, b1, w2, b2, b3, temp, xsum, w2, T, Aw, evec);
    k_fb<<<dim3(3, 8, 16), 256, 0, stream>>>(w3, Aw, Fb);
    k_out_bf<<<dim3(96, 16), 256, 0, stream>>>(Fb, xbfT, evec, out);
  } else {
    float* GpS = (float*)(ws + base);
    int nsplit = 1;
    if (base + 8 * GP1 <= ws_size) nsplit = 8;
    else if (base + 4 * GP1 <= ws_size) nsplit = 4;
    else if (base + 2 * GP1 <= ws_size) nsplit = 2;
    k_xsum<<<dim3(16 * 384), 256, 0, stream>>>(x, xsum);
    k_wcat<<<dim3(288), 256, 0, stream>>>(w1, w2, Wc);
    k_gram_f32<<<dim3(6, nsplit, 16), 256, 0, stream>>>(x, GpS, NB / nsplit);
    k_gsum<<<dim3(384, 16), 256, 0, stream>>>(GpS, Gb, nsplit);
    k_wg<<<dim3(18, 16), 256, 0, stream>>>(Wc, Gb, T);
    k_attn<<<dim3(8, 16), 256, 0, stream>>>(w1, b1, w2, b2, b3, temp, xsum, w2, T, Aw, evec);
    k_fb<<<dim3(3, 8, 16), 256, 0, stream>>>(w3, Aw, Fb);
    k_out_f32<<<dim3(96, 16), 256, 0, stream>>>(Fb, x, evec, out);
  }
}

// Round 5
// 368.178 us; speedup vs baseline: 1.4611x; 1.0592x over previous
//
#include <hip/hip_runtime.h>

// Problem constants: B=16, C=384, H=W=64 -> N=4096, HEADS=8, CH=48.
#define CB 384
#define NB 4096

typedef float f32x4 __attribute__((ext_vector_type(4)));
typedef __bf16 bf16x8 __attribute__((ext_vector_type(8)));
typedef __bf16 bf16x4 __attribute__((ext_vector_type(4)));

// ---------- helpers ----------
__device__ __forceinline__ void cvt8(const float* __restrict__ src, __bf16* dst) {
  float4 f0 = *(const float4*)src;
  float4 f1 = *(const float4*)(src + 4);
  bf16x8 v = { (__bf16)f0.x, (__bf16)f0.y, (__bf16)f0.z, (__bf16)f0.w,
               (__bf16)f1.x, (__bf16)f1.y, (__bf16)f1.z, (__bf16)f1.w };
  *(bf16x8*)dst = v;
}

// ---------- K0 (fast): x -> xbf [c][n], xbfT [n][c], xsum (atomic) ----------
// Loads batched first (16 in flight) for memory-level parallelism.
#define XT_PITCH 264
__global__ __launch_bounds__(256) void k_xbf(const float* __restrict__ x, __bf16* __restrict__ xbf,
                                             __bf16* __restrict__ xbfT, float* __restrict__ xsum) {
  int ct = blockIdx.x, nt = blockIdx.y, b = blockIdx.z;
  int c0 = ct * 64, n0 = nt * 256;
  __shared__ __bf16 tile[64][XT_PITCH];
  const float* xb = x + ((size_t)b * CB + c0) * NB + n0;
  __bf16* yb = xbf + ((size_t)b * CB + c0) * NB + n0;
  int t = threadIdx.x;
  float4 f[16];
  #pragma unroll
  for (int j = 0; j < 16; ++j) {
    int i = t + 256 * j;
    int r = i >> 6, c4 = (i & 63) * 4;
    f[j] = *(const float4*)(xb + (size_t)r * NB + c4);
  }
  #pragma unroll
  for (int j = 0; j < 16; ++j) {
    int i = t + 256 * j;
    int r = i >> 6, c4 = (i & 63) * 4;
    bf16x4 v = { (__bf16)f[j].x, (__bf16)f[j].y, (__bf16)f[j].z, (__bf16)f[j].w };
    *(bf16x4*)(yb + (size_t)r * NB + c4) = v;
    *(bf16x4*)&tile[r][c4] = v;
  }
  __syncthreads();
  {
    int row = t >> 2, q = t & 3;
    float s = 0.f;
    #pragma unroll 8
    for (int m = 0; m < 64; ++m) s += (float)tile[row][q * 64 + m];
    s += __shfl_xor(s, 1, 4);
    s += __shfl_xor(s, 2, 4);
    if (q == 0) atomicAdd(&xsum[b * CB + c0 + row], s);
  }
  __bf16* zb = xbfT + ((size_t)b * NB + n0 + t) * CB + c0;
  #pragma unroll
  for (int c8 = 0; c8 < 8; ++c8) {
    bf16x8 v;
    #pragma unroll
    for (int m = 0; m < 8; ++m) v[m] = tile[c8 * 8 + m][t];
    *(bf16x8*)(zb + c8 * 8) = v;
  }
}

// ---------- K0 (fallback): xsum only ----------
__global__ __launch_bounds__(256) void k_xsum(const float* __restrict__ x, float* __restrict__ xsum) {
  const float4* r4 = (const float4*)(x + (size_t)blockIdx.x * NB);
  float s = 0.f;
  for (int j = threadIdx.x; j < NB / 4; j += 256) { float4 f = r4[j]; s += (f.x + f.y) + (f.z + f.w); }
  #pragma unroll
  for (int off = 32; off > 0; off >>= 1) s += __shfl_down(s, off);
  __shared__ float wsum[4];
  if ((threadIdx.x & 63) == 0) wsum[threadIdx.x >> 6] = s;
  __syncthreads();
  if (threadIdx.x == 0) xsum[blockIdx.x] = (wsum[0] + wsum[1]) + (wsum[2] + wsum[3]);
}

// ---------- K0b: Wcat(bf16) = [w1; w2]  (768 x 384) ----------
__global__ __launch_bounds__(256) void k_wcat(const float* __restrict__ w1, const float* __restrict__ w2,
                                              __bf16* __restrict__ Wc) {
  int i = blockIdx.x * 256 + threadIdx.x;
  float4 f = (i < 36864) ? ((const float4*)w1)[i] : ((const float4*)w2)[i - 36864];
  __bf16* d = Wc + (size_t)i * 4;
  d[0] = (__bf16)f.x; d[1] = (__bf16)f.y; d[2] = (__bf16)f.z; d[3] = (__bf16)f.w;
}

// ---------- K1a (fast): split-K Gram partials from bf16 x ----------
__global__ __launch_bounds__(256) void k_gram_bf(const __bf16* __restrict__ xbf, float* __restrict__ Gpart,
                                                 int chunk) {
  const int TRm[6] = {0, 0, 0, 1, 1, 2};
  const int TCm[6] = {0, 1, 2, 1, 2, 2};
  int t = blockIdx.x, s = blockIdx.y, b = blockIdx.z;
  int tr = TRm[t], tc = TCm[t];
  bool diag = (tr == tc);
  const __bf16* xb = xbf + (size_t)b * CB * NB;
  __shared__ __align__(16) __bf16 As[128][72];
  __shared__ __align__(16) __bf16 Bs[128][72];
  int tid = threadIdx.x, lane = tid & 63;
  int wr = (tid >> 6) >> 1, wc = (tid >> 6) & 1;
  int rrow = lane & 15, kgrp = lane >> 4;
  f32x4 zero = {0.f, 0.f, 0.f, 0.f};
  f32x4 acc[4][4];
  #pragma unroll
  for (int i = 0; i < 4; ++i)
    #pragma unroll
    for (int j = 0; j < 4; ++j) acc[i][j] = zero;
  int sr = tid >> 1, sh = (tid & 1) * 32;
  const __bf16* pa = xb + (size_t)(tr * 128 + sr) * NB + sh;
  const __bf16* pb = xb + (size_t)(tc * 128 + sr) * NB + sh;
  int kbeg = s * chunk, kend = kbeg + chunk;
  for (int k0 = kbeg; k0 < kend; k0 += 64) {
    #pragma unroll
    for (int j = 0; j < 4; ++j) *(bf16x8*)&As[sr][sh + j * 8] = *(const bf16x8*)(pa + k0 + j * 8);
    if (!diag) {
      #pragma unroll
      for (int j = 0; j < 4; ++j) *(bf16x8*)&Bs[sr][sh + j * 8] = *(const bf16x8*)(pb + k0 + j * 8);
    }
    __syncthreads();
    const __bf16 (*Bsrc)[72] = diag ? As : Bs;
    #pragma unroll
    for (int kk = 0; kk < 2; ++kk) {
      int ko = kk * 32 + kgrp * 8;
      bf16x8 af[4], bg[4];
      #pragma unroll
      for (int i = 0; i < 4; ++i) af[i] = *(const bf16x8*)&As[wr * 64 + i * 16 + rrow][ko];
      #pragma unroll
      for (int j = 0; j < 4; ++j) bg[j] = *(const bf16x8*)&Bsrc[wc * 64 + j * 16 + rrow][ko];
      #pragma unroll
      for (int i = 0; i < 4; ++i)
        #pragma unroll
        for (int j = 0; j < 4; ++j)
          acc[i][j] = __builtin_amdgcn_mfma_f32_16x16x32_bf16(af[i], bg[j], acc[i][j], 0, 0, 0);
    }
    __syncthreads();
  }
  float* gp = Gpart + (((size_t)s * 16 + b) * 6 + t) * 16384;
  #pragma unroll
  for (int i = 0; i < 4; ++i)
    #pragma unroll
    for (int rr = 0; rr < 4; ++rr) {
      int row = wr * 64 + i * 16 + kgrp * 4 + rr;
      #pragma unroll
      for (int j = 0; j < 4; ++j) {
        int col = wc * 64 + j * 16 + rrow;
        gp[(size_t)row * 128 + col] = acc[i][j][rr];
      }
    }
}

// ---------- K1a (fallback): from fp32 x ----------
__global__ __launch_bounds__(256) void k_gram_f32(const float* __restrict__ x, float* __restrict__ Gpart,
                                                  int chunk) {
  const int TRm[6] = {0, 0, 0, 1, 1, 2};
  const int TCm[6] = {0, 1, 2, 1, 2, 2};
  int t = blockIdx.x, s = blockIdx.y, b = blockIdx.z;
  int tr = TRm[t], tc = TCm[t];
  bool diag = (tr == tc);
  const float* xb = x + (size_t)b * CB * NB;
  __shared__ __align__(16) __bf16 As[128][72];
  __shared__ __align__(16) __bf16 Bs[128][72];
  int tid = threadIdx.x, lane = tid & 63;
  int wr = (tid >> 6) >> 1, wc = (tid >> 6) & 1;
  int rrow = lane & 15, kgrp = lane >> 4;
  f32x4 zero = {0.f, 0.f, 0.f, 0.f};
  f32x4 acc[4][4];
  #pragma unroll
  for (int i = 0; i < 4; ++i)
    #pragma unroll
    for (int j = 0; j < 4; ++j) acc[i][j] = zero;
  int sr = tid >> 1, sh = (tid & 1) * 32;
  const float* pa = xb + (size_t)(tr * 128 + sr) * NB + sh;
  const float* pb = xb + (size_t)(tc * 128 + sr) * NB + sh;
  int kbeg = s * chunk, kend = kbeg + chunk;
  for (int k0 = kbeg; k0 < kend; k0 += 64) {
    #pragma unroll
    for (int j = 0; j < 4; ++j) cvt8(pa + k0 + j * 8, &As[sr][sh + j * 8]);
    if (!diag) {
      #pragma unroll
      for (int j = 0; j < 4; ++j) cvt8(pb + k0 + j * 8, &Bs[sr][sh + j * 8]);
    }
    __syncthreads();
    const __bf16 (*Bsrc)[72] = diag ? As : Bs;
    #pragma unroll
    for (int kk = 0; kk < 2; ++kk) {
      int ko = kk * 32 + kgrp * 8;
      bf16x8 af[4], bg[4];
      #pragma unroll
      for (int i = 0; i < 4; ++i) af[i] = *(const bf16x8*)&As[wr * 64 + i * 16 + rrow][ko];
      #pragma unroll
      for (int j = 0; j < 4; ++j) bg[j] = *(const bf16x8*)&Bsrc[wc * 64 + j * 16 + rrow][ko];
      #pragma unroll
      for (int i = 0; i < 4; ++i)
        #pragma unroll
        for (int j = 0; j < 4; ++j)
          acc[i][j] = __builtin_amdgcn_mfma_f32_16x16x32_bf16(af[i], bg[j], acc[i][j], 0, 0, 0);
    }
    __syncthreads();
  }
  float* gp = Gpart + (((size_t)s * 16 + b) * 6 + t) * 16384;
  #pragma unroll
  for (int i = 0; i < 4; ++i)
    #pragma unroll
    for (int rr = 0; rr < 4; ++rr) {
      int row = wr * 64 + i * 16 + kgrp * 4 + rr;
      #pragma unroll
      for (int j = 0; j < 4; ++j) {
        int col = wc * 64 + j * 16 + rrow;
        gp[(size_t)row * 128 + col] = acc[i][j][rr];
      }
    }
}

// ---------- K1b: reduce partials -> Gb(bf16), mirror off-diag ----------
__global__ __launch_bounds__(256) void k_gsum(const float* __restrict__ Gpart, __bf16* __restrict__ Gb,
                                              int nsplit) {
  const int TRm[6] = {0, 0, 0, 1, 1, 2};
  const int TCm[6] = {0, 1, 2, 1, 2, 2};
  int b = blockIdx.y;
  int idx = blockIdx.x * 256 + threadIdx.x;
  int t = idx / 16384, ij = idx & 16383;
  int i = ij >> 7, j = ij & 127;
  float s = 0.f;
  #pragma unroll 8
  for (int si = 0; si < nsplit; ++si)
    s += Gpart[(((size_t)si * 16 + b) * 6 + t) * 16384 + ij];
  int r = TRm[t] * 128 + i, c = TCm[t] * 128 + j;
  __bf16 v = (__bf16)s;
  Gb[((size_t)b * CB + r) * CB + c] = v;
  if (TRm[t] != TCm[t]) Gb[((size_t)b * CB + c) * CB + r] = v;
}

// ---------- K2: Tb_b = Wcat @ G_b -> bf16 [768][384] ----------
__global__ __launch_bounds__(256) void k_wg(const __bf16* __restrict__ Wc, const __bf16* __restrict__ Gb,
                                            __bf16* __restrict__ Tb) {
  int b = blockIdx.y;
  int tr = blockIdx.x / 3, tc = blockIdx.x % 3;
  __shared__ __align__(16) __bf16 As[128][72];
  __shared__ __align__(16) __bf16 Bs[128][72];
  int tid = threadIdx.x, lane = tid & 63;
  int wr = (tid >> 6) >> 1, wc = (tid >> 6) & 1;
  int rrow = lane & 15, kgrp = lane >> 4;
  f32x4 zero = {0.f, 0.f, 0.f, 0.f};
  f32x4 acc[4][4];
  #pragma unroll
  for (int i = 0; i < 4; ++i)
    #pragma unroll
    for (int j = 0; j < 4; ++j) acc[i][j] = zero;
  int sr = tid >> 1, sh = (tid & 1) * 32;
  const __bf16* pa = Wc + (size_t)(tr * 128 + sr) * CB + sh;
  const __bf16* pb = Gb + (size_t)b * CB * CB + (size_t)(tc * 128 + sr) * CB + sh;
  for (int k0 = 0; k0 < CB; k0 += 64) {
    #pragma unroll
    for (int j = 0; j < 4; ++j) {
      *(bf16x8*)&As[sr][sh + j * 8] = *(const bf16x8*)(pa + k0 + j * 8);
      *(bf16x8*)&Bs[sr][sh + j * 8] = *(const bf16x8*)(pb + k0 + j * 8);
    }
    __syncthreads();
    #pragma unroll
    for (int kk = 0; kk < 2; ++kk) {
      int ko = kk * 32 + kgrp * 8;
      bf16x8 af[4], bg[4];
      #pragma unroll
      for (int i = 0; i < 4; ++i) af[i] = *(const bf16x8*)&As[wr * 64 + i * 16 + rrow][ko];
      #pragma unroll
      for (int j = 0; j < 4; ++j) bg[j] = *(const bf16x8*)&Bs[wc * 64 + j * 16 + rrow][ko];
      #pragma unroll
      for (int i = 0; i < 4; ++i)
        #pragma unroll
        for (int j = 0; j < 4; ++j)
          acc[i][j] = __builtin_amdgcn_mfma_f32_16x16x32_bf16(af[i], bg[j], acc[i][j], 0, 0, 0);
    }
    __syncthreads();
  }
  __bf16* tb = Tb + (size_t)b * 768 * CB;
  #pragma unroll
  for (int i = 0; i < 4; ++i)
    #pragma unroll
    for (int rr = 0; rr < 4; ++rr) {
      int row = tr * 128 + wr * 64 + i * 16 + kgrp * 4 + rr;
      #pragma unroll
      for (int j = 0; j < 4; ++j) {
        int col = tc * 128 + wc * 64 + j * 16 + rrow;
        tb[(size_t)row * CB + col] = (__bf16)acc[i][j][rr];
      }
    }
}

// ---------- K3: per (b,h) attention algebra (round-3 proven structure, bf16 T) ----------
// grid (8, 16)
__global__ __launch_bounds__(256) void k_attn3(
    const float* __restrict__ w1, const float* __restrict__ b1,
    const float* __restrict__ w2, const float* __restrict__ b2,
    const float* __restrict__ b3,
    const float* __restrict__ temp, const float* __restrict__ xsum,
    const __bf16* __restrict__ Tb,
    float* __restrict__ Aw, float* __restrict__ evec) {
  int b = blockIdx.y, h = blockIdx.x, tid = threadIdx.x;
  int c0 = h * 48;
  __shared__ float xsuml[384];
  __shared__ float cA[48][133];
  __shared__ float cB[48][133];
  __shared__ float Sl[48][49];
  __shared__ float nq[48], nk[48], wx1[48], wx2[48];

  for (int i = tid; i < 384; i += 256) xsuml[i] = xsum[b * CB + i];
  __syncthreads();

  // phase 1 (16 lanes per row, contiguous 24-elem slices): s1 = W.row . xsum, s2 = T.row . W.row
  for (int base = 0; base < 96; base += 16) {
    int rr = base + (tid >> 4);
    int lg = tid & 15;
    int r = rr % 48;
    bool isq = rr < 48;
    const float* wrow = (isq ? w1 : w2) + (size_t)(c0 + r) * CB;
    const __bf16* trow = Tb + ((size_t)b * 768 + (isq ? 0 : 384) + c0 + r) * CB;
    int off = lg * 24;
    float wv[24], tv[24];
    #pragma unroll
    for (int u = 0; u < 6; ++u) {
      float4 fw = *(const float4*)(wrow + off + u * 4);
      wv[u * 4 + 0] = fw.x; wv[u * 4 + 1] = fw.y; wv[u * 4 + 2] = fw.z; wv[u * 4 + 3] = fw.w;
    }
    #pragma unroll
    for (int u = 0; u < 3; ++u) {
      bf16x8 t8 = *(const bf16x8*)(trow + off + u * 8);
      #pragma unroll
      for (int m = 0; m < 8; ++m) tv[u * 8 + m] = (float)t8[m];
    }
    float s1 = 0.f, s2 = 0.f;
    #pragma unroll
    for (int e = 0; e < 24; ++e) { s1 += wv[e] * xsuml[off + e]; s2 += wv[e] * tv[e]; }
    #pragma unroll
    for (int o = 8; o > 0; o >>= 1) {
      s1 += __shfl_xor(s1, o, 16);
      s2 += __shfl_xor(s2, o, 16);
    }
    if (lg == 0) {
      float bb = (isq ? b1 : b2)[c0 + r];
      float n2 = s2 + 2.f * bb * s1 + 4096.f * bb * bb;
      float nv = fmaxf(sqrtf(fmaxf(n2, 0.f)), 1e-12f);
      if (isq) { wx1[r] = s1; nq[r] = nv; } else { wx2[r] = s1; nk[r] = nv; }
    }
  }
  __syncthreads();

  // phase 2: S = T1 @ W2_h^T, chunked over e
  float sacc[12];
  #pragma unroll
  for (int i = 0; i < 12; ++i) sacc[i] = 0.f;
  int cc = tid % 48, dq = tid / 48;
  for (int ch = 0; ch < 3; ++ch) {
    for (int idx = tid; idx < 768; idx += 256) {
      int row = idx >> 4, q8 = (idx & 15) * 8;
      bf16x8 t8 = *(const bf16x8*)(Tb + ((size_t)b * 768 + c0 + row) * CB + ch * 128 + q8);
      #pragma unroll
      for (int m = 0; m < 8; ++m) cA[row][q8 + m] = (float)t8[m];
    }
    for (int idx = tid; idx < 1536; idx += 256) {
      int row = idx >> 5, q4 = (idx & 31) * 4;
      float4 fw = *(const float4*)(w2 + (size_t)(c0 + row) * CB + ch * 128 + q4);
      cB[row][q4 + 0] = fw.x; cB[row][q4 + 1] = fw.y; cB[row][q4 + 2] = fw.z; cB[row][q4 + 3] = fw.w;
    }
    __syncthreads();
    if (tid < 192) {
      for (int e = 0; e < 128; ++e) {
        float av = cA[cc][e];
        #pragma unroll
        for (int i = 0; i < 12; ++i) sacc[i] += av * cB[dq * 12 + i][e];
      }
    }
    __syncthreads();
  }
  if (tid < 192) {
    float b1c = b1[c0 + cc];
    float th = temp[h];
    #pragma unroll
    for (int i = 0; i < 12; ++i) {
      int d = dq * 12 + i;
      float b2d = b2[c0 + d];
      float sraw = sacc[i] + b1c * wx2[d] + b2d * wx1[cc] + 4096.f * b1c * b2d;
      Sl[cc][d] = th * sraw / (nq[cc] * nk[d]);
    }
  }
  __syncthreads();

  // phase 3: softmax rows + evec + attn probs (round-3 proven)
  if (tid < 48) {
    float m = -1e30f;
    #pragma unroll 4
    for (int d = 0; d < 48; ++d) m = fmaxf(m, Sl[tid][d]);
    float ssum = 0.f;
    #pragma unroll 4
    for (int d = 0; d < 48; ++d) { float p = __expf(Sl[tid][d] - m); Sl[tid][d] = p; ssum += p; }
    float inv = 1.f / ssum;
    float ev = 0.f;
    float* arow = Aw + (((size_t)b * 8 + h) * 48 + tid) * 48;
    #pragma unroll 4
    for (int d = 0; d < 48; ++d) {
      float a_ = Sl[tid][d] * inv;
      arow[d] = a_;
      ev += a_ * b3[c0 + d];
    }
    evec[b * CB + c0 + tid] = b3[c0 + tid] + ev;
  }
}

// ---------- K3b: F rows -> bf16 ----------
__global__ __launch_bounds__(256) void k_fb(const float* __restrict__ w3, const float* __restrict__ Aw,
                                            __bf16* __restrict__ Fb) {
  int ch = blockIdx.x, h = blockIdx.y, b = blockIdx.z;
  int c0 = h * 48, tid = threadIdx.x;
  __shared__ float a_s[48][49];
  __shared__ float w_s[48][129];
  const float* ab = Aw + ((size_t)b * 8 + h) * 2304;
  for (int idx = tid; idx < 2304; idx += 256) a_s[idx / 48][idx % 48] = ab[idx];
  for (int idx = tid; idx < 1536; idx += 256) {
    int row = idx >> 5, q4 = (idx & 31) * 4;
    float4 fw = *(const float4*)(w3 + (size_t)(c0 + row) * CB + ch * 128 + q4);
    w_s[row][q4 + 0] = fw.x; w_s[row][q4 + 1] = fw.y; w_s[row][q4 + 2] = fw.z; w_s[row][q4 + 3] = fw.w;
  }
  __syncthreads();
  for (int idx = tid; idx < 6144; idx += 256) {
    int c = idx >> 7, a = idx & 127;
    float acc = w_s[c][a];
    #pragma unroll 8
    for (int d = 0; d < 48; ++d) acc += a_s[c][d] * w_s[d][a];
    int ga = ch * 128 + a;
    float val = acc + ((ga == c0 + c) ? 1.f : 0.f);
    Fb[((size_t)b * CB + c0 + c) * CB + ga] = (__bf16)val;
  }
}

// ---------- K4 (fast): out = F @ x + e, B from xbfT ----------
__global__ __launch_bounds__(256) void k_out_bf(const __bf16* __restrict__ Fb, const __bf16* __restrict__ xbfT,
                                                const float* __restrict__ evec, float* __restrict__ out) {
  int b = blockIdx.y;
  int tr = blockIdx.x % 3, tn = blockIdx.x / 3;
  __shared__ __align__(16) __bf16 As[128][72];
  __shared__ __align__(16) __bf16 Bs[128][72];
  int tid = threadIdx.x, lane = tid & 63;
  int wr = (tid >> 6) >> 1, wc = (tid >> 6) & 1;
  int rrow = lane & 15, kgrp = lane >> 4;
  f32x4 zero = {0.f, 0.f, 0.f, 0.f};
  f32x4 acc[4][4];
  #pragma unroll
  for (int i = 0; i < 4; ++i)
    #pragma unroll
    for (int j = 0; j < 4; ++j) acc[i][j] = zero;
  int sr = tid >> 1, sh = (tid & 1) * 32;
  const __bf16* pa = Fb + ((size_t)b * CB + tr * 128 + sr) * CB + sh;
  const __bf16* pb = xbfT + ((size_t)b * NB + tn * 128 + sr) * CB + sh;
  for (int k0 = 0; k0 < CB; k0 += 64) {
    #pragma unroll
    for (int j = 0; j < 4; ++j) {
      *(bf16x8*)&As[sr][sh + j * 8] = *(const bf16x8*)(pa + k0 + j * 8);
      *(bf16x8*)&Bs[sr][sh + j * 8] = *(const bf16x8*)(pb + k0 + j * 8);
    }
    __syncthreads();
    #pragma unroll
    for (int kk = 0; kk < 2; ++kk) {
      int ko = kk * 32 + kgrp * 8;
      bf16x8 af[4], bg[4];
      #pragma unroll
      for (int i = 0; i < 4; ++i) af[i] = *(const bf16x8*)&As[wr * 64 + i * 16 + rrow][ko];
      #pragma unroll
      for (int j = 0; j < 4; ++j) bg[j] = *(const bf16x8*)&Bs[wc * 64 + j * 16 + rrow][ko];
      #pragma unroll
      for (int i = 0; i < 4; ++i)
        #pragma unroll
        for (int j = 0; j < 4; ++j)
          acc[i][j] = __builtin_amdgcn_mfma_f32_16x16x32_bf16(af[i], bg[j], acc[i][j], 0, 0, 0);
    }
    __syncthreads();
  }
  float* ob = out + (size_t)b * CB * NB;
  #pragma unroll
  for (int i = 0; i < 4; ++i)
    #pragma unroll
    for (int rr = 0; rr < 4; ++rr) {
      int row = tr * 128 + wr * 64 + i * 16 + kgrp * 4 + rr;
      float ev = evec[b * CB + row];
      #pragma unroll
      for (int j = 0; j < 4; ++j) {
        int col = tn * 128 + wc * 64 + j * 16 + rrow;
        ob[(size_t)row * NB + col] = acc[i][j][rr] + ev;
      }
    }
}

// ---------- K4 (fallback): B staged from fp32 x with transpose ----------
__global__ __launch_bounds__(256) void k_out_f32(const __bf16* __restrict__ Fb, const float* __restrict__ x,
                                                 const float* __restrict__ evec, float* __restrict__ out) {
  int b = blockIdx.y;
  int tr = blockIdx.x % 3, tn = blockIdx.x / 3;
  __shared__ __align__(16) __bf16 As[128][72];
  __shared__ __align__(16) __bf16 Bs[128][72];
  int tid = threadIdx.x, lane = tid & 63;
  int wr = (tid >> 6) >> 1, wc = (tid >> 6) & 1;
  int rrow = lane & 15, kgrp = lane >> 4;
  f32x4 zero = {0.f, 0.f, 0.f, 0.f};
  f32x4 acc[4][4];
  #pragma unroll
  for (int i = 0; i < 4; ++i)
    #pragma unroll
    for (int j = 0; j < 4; ++j) acc[i][j] = zero;
  int sr = tid >> 1, sh = (tid & 1) * 32;
  const __bf16* pa = Fb + ((size_t)b * CB + tr * 128 + sr) * CB + sh;
  int ba = tid >> 2, bq = tid & 3;
  const float* pxbase = x + ((size_t)b * CB + ba) * NB + tn * 128 + bq * 32;
  for (int k0 = 0; k0 < CB; k0 += 64) {
    #pragma unroll
    for (int j = 0; j < 4; ++j)
      *(bf16x8*)&As[sr][sh + j * 8] = *(const bf16x8*)(pa + k0 + j * 8);
    const float* px = pxbase + (size_t)k0 * NB;
    #pragma unroll
    for (int j = 0; j < 32; j += 4) {
      float4 f = *(const float4*)(px + j);
      int nl = bq * 32 + j;
      Bs[nl + 0][ba] = (__bf16)f.x; Bs[nl + 1][ba] = (__bf16)f.y;
      Bs[nl + 2][ba] = (__bf16)f.z; Bs[nl + 3][ba] = (__bf16)f.w;
    }
    __syncthreads();
    #pragma unroll
    for (int kk = 0; kk < 2; ++kk) {
      int ko = kk * 32 + kgrp * 8;
      bf16x8 af[4], bg[4];
      #pragma unroll
      for (int i = 0; i < 4; ++i) af[i] = *(const bf16x8*)&As[wr * 64 + i * 16 + rrow][ko];
      #pragma unroll
      for (int j = 0; j < 4; ++j) bg[j] = *(const bf16x8*)&Bs[wc * 64 + j * 16 + rrow][ko];
      #pragma unroll
      for (int i = 0; i < 4; ++i)
        #pragma unroll
        for (int j = 0; j < 4; ++j)
          acc[i][j] = __builtin_amdgcn_mfma_f32_16x16x32_bf16(af[i], bg[j], acc[i][j], 0, 0, 0);
    }
    __syncthreads();
  }
  float* ob = out + (size_t)b * CB * NB;
  #pragma unroll
  for (int i = 0; i < 4; ++i)
    #pragma unroll
    for (int rr = 0; rr < 4; ++rr) {
      int row = tr * 128 + wr * 64 + i * 16 + kgrp * 4 + rr;
      float ev = evec[b * CB + row];
      #pragma unroll
      for (int j = 0; j < 4; ++j) {
        int col = tn * 128 + wc * 64 + j * 16 + rrow;
        ob[(size_t)row * NB + col] = acc[i][j][rr] + ev;
      }
    }
}

extern "C" void kernel_launch(void* const* d_in, const int* in_sizes, int n_in,
                              void* d_out, int out_size, void* d_ws, size_t ws_size,
                              hipStream_t stream) {
  const float* x  = (const float*)d_in[0];
  const float* w1 = (const float*)d_in[1];
  const float* b1 = (const float*)d_in[2];
  const float* w2 = (const float*)d_in[3];
  const float* b2 = (const float*)d_in[4];
  const float* w3 = (const float*)d_in[5];
  const float* b3 = (const float*)d_in[6];
  const float* temp = (const float*)d_in[7];
  float* out = (float*)d_out;

  char* ws = (char*)d_ws;
  float*  xsum = (float*)(ws);                  // 24,576
  __bf16* Wc   = (__bf16*)(ws + 24576);         // 589,824
  __bf16* Gb   = (__bf16*)(ws + 614400);        // 4,718,592
  __bf16* Tb   = (__bf16*)(ws + 5332992);       // 9,437,184 (bf16)
  __bf16* Fb   = (__bf16*)(ws + 14770176);      // 4,718,592
  float*  evec = (float*)(ws + 19488768);       // 24,576
  float*  Aw   = (float*)(ws + 19513344);       // 1,179,648 -> ends 20,692,992

  const size_t base = 20692992ull;
  const size_t XBF_BYTES = 50331648ull;   // 16*384*4096*2
  const size_t GP1 = 6291456ull;

  __bf16* xbf  = (__bf16*)(ws + base);
  __bf16* xbfT = (__bf16*)(ws + base + XBF_BYTES);
  float*  GpF  = (float*)(ws + base + 2 * XBF_BYTES);

  int nsplit_fast = 0;
  size_t fbase = base + 2 * XBF_BYTES;
  if (fbase + 8 * GP1 <= ws_size) nsplit_fast = 8;
  else if (fbase + 4 * GP1 <= ws_size) nsplit_fast = 4;
  else if (fbase + 2 * GP1 <= ws_size) nsplit_fast = 2;
  else if (fbase + 1 * GP1 <= ws_size) nsplit_fast = 1;

  if (nsplit_fast > 0) {
    hipMemsetAsync(xsum, 0, 24576, stream);
    k_xbf<<<dim3(6, 16, 16), 256, 0, stream>>>(x, xbf, xbfT, xsum);
    k_wcat<<<dim3(288), 256, 0, stream>>>(w1, w2, Wc);
    k_gram_bf<<<dim3(6, nsplit_fast, 16), 256, 0, stream>>>(xbf, GpF, NB / nsplit_fast);
    k_gsum<<<dim3(384, 16), 256, 0, stream>>>(GpF, Gb, nsplit_fast);
    k_wg<<<dim3(18, 16), 256, 0, stream>>>(Wc, Gb, Tb);
    k_attn3<<<dim3(8, 16), 256, 0, stream>>>(w1, b1, w2, b2, b3, temp, xsum, Tb, Aw, evec);
    k_fb<<<dim3(3, 8, 16), 256, 0, stream>>>(w3, Aw, Fb);
    k_out_bf<<<dim3(96, 16), 256, 0, stream>>>(Fb, xbfT, evec, out);
  } else {
    float* GpS = (float*)(ws + base);
    int nsplit = 1;
    if (base + 8 * GP1 <= ws_size) nsplit = 8;
    else if (base + 4 * GP1 <= ws_size) nsplit = 4;
    else if (base + 2 * GP1 <= ws_size) nsplit = 2;
    k_xsum<<<dim3(16 * 384), 256, 0, stream>>>(x, xsum);
    k_wcat<<<dim3(288), 256, 0, stream>>>(w1, w2, Wc);
    k_gram_f32<<<dim3(6, nsplit, 16), 256, 0, stream>>>(x, GpS, NB / nsplit);
    k_gsum<<<dim3(384, 16), 256, 0, stream>>>(GpS, Gb, nsplit);
    k_wg<<<dim3(18, 16), 256, 0, stream>>>(Wc, Gb, Tb);
    k_attn3<<<dim3(8, 16), 256, 0, stream>>>(w1, b1, w2, b2, b3, temp, xsum, Tb, Aw, evec);
    k_fb<<<dim3(3, 8, 16), 256, 0, stream>>>(w3, Aw, Fb);
    k_out_f32<<<dim3(96, 16), 256, 0, stream>>>(Fb, x, evec, out);
  }
}